// Round 5
// baseline (375.097 us; speedup 1.0000x reference)
//
#include <hip/hip_runtime.h>
#include <stdint.h>
#include <stddef.h>

// ---------------- common helpers ----------------

typedef __bf16 bf16x8 __attribute__((ext_vector_type(8)));
typedef float  f32x4  __attribute__((ext_vector_type(4)));

#define MFMA16x16(a,b,c) __builtin_amdgcn_mfma_f32_16x16x32_bf16((a),(b),(c),0,0,0)

__device__ __forceinline__ uint16_t f2bf(float f){
  union { float f; uint32_t u; } v; v.f = f;
  uint32_t u = v.u + 0x7fffu + ((v.u >> 16) & 1u);
  return (uint16_t)(u >> 16);
}
__device__ __forceinline__ bf16x8 load_frag(const uint16_t* p){
  uint4 u = *reinterpret_cast<const uint4*>(p);
  return __builtin_bit_cast(bf16x8, u);
}
__device__ __forceinline__ f32x4 fzero(){
  f32x4 z = {0.f, 0.f, 0.f, 0.f};
  return z;
}
__device__ __forceinline__ uint32_t pack2(float a, float b){
  return (uint32_t)f2bf(a) | ((uint32_t)f2bf(b) << 16);
}
// async global->LDS DMA, 16B per lane, LDS dst = wave-uniform base + lane*16
__device__ __forceinline__ void gl2lds16(const uint16_t* g, uint16_t* l){
  __builtin_amdgcn_global_load_lds(
      (const __attribute__((address_space(1))) uint32_t*)g,
      (__attribute__((address_space(3))) uint32_t*)l,
      16, 0, 0);
}

// ---------------- 1) transpose + f32->bf16 convert ----------------
__global__ __launch_bounds__(256) void k_transpose_cvt(const float* __restrict__ in,
                                                       uint16_t* __restrict__ out,
                                                       int R, int C){
  __shared__ float t[32][33];
  const int tc = blockIdx.x * 32;
  const int tr = blockIdx.y * 32;
  const int j = threadIdx.x & 31, i0 = threadIdx.x >> 5;
  for(int ii = 0; ii < 4; ++ii){
    int r = i0 + ii * 8;
    t[r][j] = in[(size_t)(tr + r) * C + tc + j];
  }
  __syncthreads();
  for(int ii = 0; ii < 4; ++ii){
    int c = i0 + ii * 8;
    out[(size_t)(tc + c) * R + tr + j] = f2bf(t[j][c]);
  }
}

// ---------------- 2) down-proj + RMSNorm via MFMA ----------------
__global__ __launch_bounds__(256) void k_down_mfma(const float* __restrict__ x,
                                                   const uint16_t* __restrict__ wdt,
                                                   const float* __restrict__ rms_w,
                                                   uint16_t* __restrict__ h_out){
  __shared__ __align__(16) uint16_t as[32 * 64];
  __shared__ float hsq[32];
  const int tid  = threadIdx.x;
  const int wave = tid >> 6, lane = tid & 63;
  const int ml = lane & 15, qd = lane >> 4;
  const int m0 = blockIdx.x * 32;
  const int n0w = wave * 48;
  if(tid < 32) hsq[tid] = 0.f;

  f32x4 acc[2][3];
#pragma unroll
  for(int mt = 0; mt < 2; ++mt)
#pragma unroll
    for(int nt = 0; nt < 3; ++nt) acc[mt][nt] = fzero();

  const int srow = tid >> 3, sc = tid & 7;
  for(int kt = 0; kt < 16; ++kt){
    const float* src = x + (size_t)(m0 + srow) * 1024 + kt * 64 + sc * 8;
    float4 a = *reinterpret_cast<const float4*>(src);
    float4 b = *reinterpret_cast<const float4*>(src + 4);
    uint4 pk;
    pk.x = pack2(a.x, a.y); pk.y = pack2(a.z, a.w);
    pk.z = pack2(b.x, b.y); pk.w = pack2(b.z, b.w);
    __syncthreads();
    *reinterpret_cast<uint4*>(as + srow * 64 + ((sc ^ (srow & 7)) * 8)) = pk;
    __syncthreads();
#pragma unroll
    for(int kk = 0; kk < 2; ++kk){
      bf16x8 af[2];
#pragma unroll
      for(int mt = 0; mt < 2; ++mt){
        int row = mt * 16 + ml;
        af[mt] = load_frag(as + row * 64 + (((kk * 4 + qd) ^ (row & 7)) * 8));
      }
#pragma unroll
      for(int nt = 0; nt < 3; ++nt){
        bf16x8 bfr = load_frag(wdt + (size_t)(n0w + nt * 16 + ml) * 1024 + kt * 64 + kk * 32 + qd * 8);
#pragma unroll
        for(int mt = 0; mt < 2; ++mt)
          acc[mt][nt] = MFMA16x16(af[mt], bfr, acc[mt][nt]);
      }
    }
  }
  __syncthreads();
#pragma unroll
  for(int mt = 0; mt < 2; ++mt)
#pragma unroll
    for(int r = 0; r < 4; ++r){
      float s = acc[mt][0][r]*acc[mt][0][r] + acc[mt][1][r]*acc[mt][1][r] + acc[mt][2][r]*acc[mt][2][r];
#pragma unroll
      for(int off = 1; off < 16; off <<= 1) s += __shfl_xor(s, off);
      if(ml == 0) atomicAdd(&hsq[mt * 16 + qd * 4 + r], s);
    }
  __syncthreads();
  float rw[3];
#pragma unroll
  for(int nt = 0; nt < 3; ++nt) rw[nt] = rms_w[n0w + nt * 16 + ml];
#pragma unroll
  for(int mt = 0; mt < 2; ++mt)
#pragma unroll
    for(int r = 0; r < 4; ++r){
      int row = mt * 16 + qd * 4 + r;
      float scl = rsqrtf(hsq[row] * (1.0f / 192.0f) + 1e-6f);
#pragma unroll
      for(int nt = 0; nt < 3; ++nt)
        h_out[(size_t)(m0 + row) * 192 + n0w + nt * 16 + ml] = f2bf(acc[mt][nt][r] * scl * rw[nt]);
    }
}

// ---------------- 3) up-proj GEMM v2: LDS repack -> full-line stores --------
__global__ __launch_bounds__(256) void k_gemm_up(const uint16_t* __restrict__ hmat,
                                                 const uint16_t* __restrict__ wt,
                                                 uint16_t* __restrict__ q_t,
                                                 uint16_t* __restrict__ k_t,
                                                 uint16_t* __restrict__ v_t){
  __shared__ __align__(16) uint16_t rp[16 * 129 * 8];   // 33,024 B
  const int wave = threadIdx.x >> 6, lane = threadIdx.x & 63;
  const int ml = lane & 15, qd = lane >> 4;
  const int m0 = blockIdx.y * 32;
  const int bx = blockIdx.x;
  const int which = bx / 6;                // 0=q 1=k 2=v
  const int d0b = (bx % 6) * 32;
  const int n0w = bx * 512 + wave * 128;
  const int d0w = d0b + wave * 8;

  bf16x8 af[2][6];
#pragma unroll
  for(int mt = 0; mt < 2; ++mt)
#pragma unroll
    for(int kk = 0; kk < 6; ++kk)
      af[mt][kk] = load_frag(hmat + (size_t)(m0 + mt * 16 + ml) * 192 + kk * 32 + qd * 8);

  f32x4 acc[8][2];
#pragma unroll
  for(int nt = 0; nt < 8; ++nt){ acc[nt][0] = fzero(); acc[nt][1] = fzero(); }
#pragma unroll
  for(int nt = 0; nt < 8; ++nt){
#pragma unroll
    for(int kk = 0; kk < 6; ++kk){
      bf16x8 b = load_frag(wt + (size_t)(n0w + nt * 16 + ml) * 192 + kk * 32 + qd * 8);
      acc[nt][0] = MFMA16x16(af[0][kk], b, acc[nt][0]);
      acc[nt][1] = MFMA16x16(af[1][kk], b, acc[nt][1]);
    }
  }

  const int b   = m0 >> 11;
  const int s0  = m0 & 2047;
  const int kt2 = s0 >> 6;
  const int row0 = s0 & 63;                // 32-aligned: rs bits come from t
  uint4* rp4 = (uint4*)rp;

  if(which < 2){
    const float qs = which ? 1.0f : 0.07216878364870322f;   // fold 1/sqrt(192) into Q
    const bool rope = (d0w >= 128) && (d0w < 160);
#pragma unroll
    for(int mt = 0; mt < 2; ++mt)
#pragma unroll
      for(int r = 0; r < 4; ++r){
        int t = mt * 16 + qd * 4 + r;
        int s = s0 + t;
        float v[8];
#pragma unroll
        for(int nt = 0; nt < 8; ++nt) v[nt] = acc[nt][mt][r] * qs;
        if(rope){
#pragma unroll
          for(int pi = 0; pi < 4; ++pi){
            int fi = (d0w + 2 * pi - 128) >> 1;
            float invf = __expf(-(float)fi * 0.5756462732485114f); // ln(10000)/16
            float sn, cs;
            sincosf((float)s * invf, &sn, &cs);
            float e = v[2 * pi], o = v[2 * pi + 1];
            v[2 * pi]     = e * cs - o * sn;
            v[2 * pi + 1] = o * cs + e * sn;
          }
        }
        uint4 pk;
        pk.x = pack2(v[0], v[1]); pk.y = pack2(v[2], v[3]);
        pk.z = pack2(v[4], v[5]); pk.w = pack2(v[6], v[7]);
        rp4[ml * 129 + t * 4 + (wave ^ (t & 3))] = pk;
      }
  } else {
#pragma unroll
    for(int nt = 0; nt < 8; ++nt){
      int dl = wave * 8 + nt;
#pragma unroll
      for(int mt = 0; mt < 2; ++mt){
        int jc = mt * 2 + (qd >> 1);
        int slot = ml * 129 + dl * 4 + (jc ^ (dl & 3));
        uint2 pk;
        pk.x = pack2(acc[nt][mt][0], acc[nt][mt][1]);
        pk.y = pack2(acc[nt][mt][2], acc[nt][mt][3]);
        *(reinterpret_cast<uint2*>(rp + slot * 8) + (qd & 1)) = pk;
      }
    }
  }
  __syncthreads();

  if(which < 2){
    uint16_t* dst = which ? k_t : q_t;
    const int cb = d0b >> 3;
#pragma unroll
    for(int it = 0; it < 8; ++it){
      int h = wave * 4 + (it & 3), rhalf = it >> 2;
      int tloc = rhalf * 16 + (lane >> 2), p = lane & 3;
      int row = row0 + tloc;
      uint4 val = rp4[h * 129 + tloc * 4 + p];
      size_t off = ((size_t)(b * 16 + h) * 32 + kt2) * 12288
                 + (size_t)row * 192 + ((cb ^ (tloc & 4)) + p) * 8;
      *reinterpret_cast<uint4*>(dst + off) = val;
    }
  } else {
    const int cs0 = row0 >> 3;
#pragma unroll
    for(int it = 0; it < 8; ++it){
      int h = wave * 4 + (it & 3), dhalf = it >> 2;
      int dl = dhalf * 16 + (lane >> 2), p = lane & 3;
      uint4 val = rp4[h * 129 + dl * 4 + p];
      size_t off = ((size_t)(b * 16 + h) * 32 + kt2) * 12288
                 + (size_t)(d0b + dl) * 64 + ((cs0 ^ (dl & 4)) + p) * 8;
      *reinterpret_cast<uint4*>(v_t + off) = val;
    }
  }
}

// ---------------- 4) causal flash attention v7 ----------------
// Key change vs R0-R3: each wave owns 32 q-rows (2 q-tiles), so every K/V
// fragment read from LDS feeds 2 MFMAs (27 ds_read_b128 per 50 MFMA, 0.54:1
// vs 1:1 before). All prior variants were LDS-read-pipe-bound at ~25% MfmaUtil.
// 512 blocks x 256 threads (4 waves); block = 128-row q-block.
// qb = (bx<256) ? 15-(bx>>5) : (bx>>5)-8  -> round-robin CU pairs sum to 68
// iters. KVBLK=32, K/V double-buffered with counted vmcnt(6) (R0's pipeline),
// 6 DMAs/wave/iter. LDS 61,440 B -> 2 blocks/CU. launch_bounds(256,2):
// 256-reg cap under BOTH waves/EU and blocks/CU semantics.
// Q fragments loaded directly global->regs (no LDS staging).
// K/V/psw layouts carried verbatim from the R3-verified kernel.
__global__ __launch_bounds__(256, 2) void k_attn(const uint16_t* __restrict__ q_t,
                                                 const uint16_t* __restrict__ k_t,
                                                 const uint16_t* __restrict__ v_t,
                                                 uint16_t* __restrict__ attn_out){
  // carve (elems): kb0[6144] kb1[6144] vb0[6656] vb1[6656] psw[4*1280] = 30720
  __shared__ __align__(16) uint16_t smem[30720];
  const int tid  = threadIdx.x;
  const int wave = tid >> 6;
  const int lane = tid & 63;
  const int ml   = lane & 15;
  const int qd   = lane >> 4;
  const int bx   = blockIdx.x;
  const int bh   = bx & 31;
  const int qb   = (bx < 256) ? (15 - (bx >> 5)) : ((bx >> 5) - 8);
  const int last = 4 * qb + 3;

  uint16_t* const kb0 = smem;                 // 32 x 192
  uint16_t* const kb1 = smem + 6144;
  uint16_t* const vb0 = smem + 12288;         // 208 x 32-key (rows 192.. = ones)
  uint16_t* const vb1 = smem + 18944;
  uint16_t* const psw = smem + 25600 + wave * 1280;   // [32][40] per wave

  const uint16_t* kbase = k_t + (size_t)bh * 393216;
  const uint16_t* vbase = v_t + (size_t)bh * 393216;
  const int hh = bh & 15, bb = bh >> 4;

  // V gather constants (verified R3): lane L of seg g fills LDS elems
  // g*512+L*8; source elem = d*64 + (((h*4+c)^(d&7))*8).
  const int c_  = (lane & 3) ^ ((lane >> 3) & 3);
  const int s7_ = (lane >> 2) & 7;
  const int vg_ = (lane >> 2) * 64;
  const int voff0 = vg_ + ((c_ ^ s7_) * 8);
  const int voff1 = vg_ + (((4 + c_) ^ s7_) * 8);
  // PV read base: addr = vb + dt*512 + vpo (verified R3)
  const int vpo = ml * 32 + ((qd ^ ((ml >> 1) & 3)) * 8);

  // ---- Q fragments: direct global->regs, 2 q-tiles x 6 kk ----
  bf16x8 qf[2][6];
  {
    const int row = wave * 16 + ml;
    const int sw = row & 7;
#pragma unroll
    for(int t = 0; t < 2; ++t){
      const uint16_t* qtb = q_t + ((size_t)bh * 32 + qb * 2 + t) * 12288 + (size_t)row * 192;
#pragma unroll
      for(int kk = 0; kk < 6; ++kk)
        qf[t][kk] = load_frag(qtb + (((kk * 4 + qd) ^ sw) * 8));
    }
  }
  __builtin_amdgcn_sched_barrier(0);
  asm volatile("s_waitcnt vmcnt(0)" ::: "memory");
  __builtin_amdgcn_sched_barrier(0);

  // ones rows of both V buffers (softmax-denominator source), 512 elems each
  ((uint32_t*)(vb0 + 6144))[tid] = 0x3F803F80u;
  ((uint32_t*)(vb1 + 6144))[tid] = 0x3F803F80u;

  // stage KV tile kt (32 keys) into buffer sel: 3 K + 3 V DMAs per wave
  auto stageKV = [&](int kt, int sel){
    const uint16_t* ksrc = kbase + (size_t)(kt >> 1) * 12288 + (kt & 1) * 6144
                         + wave * 1536 + lane * 8;
    uint16_t* kd = (sel ? kb1 : kb0) + wave * 1536;
    gl2lds16(ksrc,        kd);
    gl2lds16(ksrc + 512,  kd + 512);
    gl2lds16(ksrc + 1024, kd + 1024);
    const int vo = (kt & 1) ? voff1 : voff0;
    const uint16_t* vsrc = vbase + (size_t)(kt >> 1) * 12288 + (size_t)(wave * 3) * 1024 + vo;
    uint16_t* vd = (sel ? vb1 : vb0) + wave * 1536;
    gl2lds16(vsrc,        vd);
    gl2lds16(vsrc + 1024, vd + 512);
    gl2lds16(vsrc + 2048, vd + 1024);
  };

  stageKV(0, 0);
  asm volatile("s_waitcnt lgkmcnt(0)" ::: "memory");   // ones writes visible

  f32x4 o[2][13];
#pragma unroll
  for(int t = 0; t < 2; ++t)
#pragma unroll
    for(int i = 0; i < 13; ++i) o[t][i] = fzero();

  const int r0 = qb * 128 + wave * 16;       // tile-0 first q-row
  const int r1 = r0 + 64;                    // tile-1 first q-row
  int cur = 0;
  for(int kt = 0; kt <= last; ++kt){
    if(kt < last){
      stageKV(kt + 1, cur ^ 1);
      __builtin_amdgcn_sched_barrier(0);
      asm volatile("s_waitcnt vmcnt(6)" ::: "memory");   // tile kt landed
      __builtin_amdgcn_sched_barrier(0);
    } else {
      asm volatile("s_waitcnt vmcnt(0)" ::: "memory");
      __builtin_amdgcn_sched_barrier(0);
    }
    __builtin_amdgcn_s_barrier();            // [A] tile kt staged everywhere

    const int kl = kt * 32;
    if(kl <= r1 + 15){                       // wave has work this tile
      const uint16_t* kc = cur ? kb1 : kb0;
      const uint16_t* vc = cur ? vb1 : vb0;
      const bool a0 = (kl <= r0 + 15);       // tile-0 active (uniform)

      f32x4 s[2][2];
      s[0][0] = fzero(); s[0][1] = fzero(); s[1][0] = fzero(); s[1][1] = fzero();
      __builtin_amdgcn_s_setprio(1);
#pragma unroll
      for(int nt = 0; nt < 2; ++nt){
        int row = nt * 16 + ml;
#pragma unroll
        for(int kk = 0; kk < 6; ++kk){
          bf16x8 bfr = load_frag(kc + row * 192 + (((kk * 4 + qd) ^ (row & 7)) * 8));
          if(a0) s[0][nt] = MFMA16x16(qf[0][kk], bfr, s[0][nt]);
          s[1][nt] = MFMA16x16(qf[1][kk], bfr, s[1][nt]);
        }
      }
      __builtin_amdgcn_s_setprio(0);

#pragma unroll
      for(int t = 0; t < 2; ++t){
        if(t == 0 && !a0) continue;
        const int rq = t ? r1 : r0;
        const bool diag = (kl + 31 > rq);
#pragma unroll
        for(int nt = 0; nt < 2; ++nt)
#pragma unroll
          for(int r = 0; r < 4; ++r){
            float v = s[t][nt][r];
            if(diag){
              int i = rq + qd * 4 + r;
              int j = kl + nt * 16 + ml;
              if(j > i) v = -1e9f;
            }
            psw[(t * 16 + qd * 4 + r) * 40 + nt * 16 + ml] = f2bf(__expf(v));
          }
      }
      bf16x8 pa0 = load_frag(psw + ml * 40 + qd * 8);
      bf16x8 pa1 = load_frag(psw + (16 + ml) * 40 + qd * 8);
      __builtin_amdgcn_s_setprio(1);
#pragma unroll
      for(int dt = 0; dt < 13; ++dt){
        bf16x8 vbf = load_frag(vc + dt * 512 + vpo);
        if(a0) o[0][dt] = MFMA16x16(pa0, vbf, o[0][dt]);
        o[1][dt] = MFMA16x16(pa1, vbf, o[1][dt]);
      }
      __builtin_amdgcn_s_setprio(0);
    }
    __builtin_amdgcn_s_barrier();            // [B] all reads of tile kt done
    cur ^= 1;
  }

  // ---- epilogue: 2 q-tiles x 16 rows per wave ----
#pragma unroll
  for(int t = 0; t < 2; ++t){
    const int rq = t ? r1 : r0;
#pragma unroll
    for(int r = 0; r < 4; ++r){
      int i = rq + qd * 4 + r;
      float inv = 1.0f / o[t][12][r];
      size_t obase = ((size_t)bb * 2048 + i) * 3072 + hh * 192;
#pragma unroll
      for(int dt = 0; dt < 12; ++dt)
        attn_out[obase + dt * 16 + ml] = f2bf(o[t][dt][r] * inv);
    }
  }
}

// ---------------- 5) out-proj GEMM: m97-style LDS-tiled, split-K=2 ----------
__global__ __launch_bounds__(256) void k_gemm_o_tile(const uint16_t* __restrict__ a,
                                                     const uint16_t* __restrict__ wt,
                                                     float* __restrict__ part){
  __shared__ __align__(16) uint16_t as[128 * 64];
  __shared__ __align__(16) uint16_t bs[128 * 64];
  const int wave = threadIdx.x >> 6, lane = threadIdx.x & 63;
  const int ml = lane & 15, qd = lane >> 4;
  const int m0 = blockIdx.y * 128, n0 = blockIdx.x * 128;
  const int kz = blockIdx.z;
  const int mo = (wave >> 1) * 64, no = (wave & 1) * 64;

  const int lrow = lane >> 3;
  const int gch  = (lane & 7) ^ (lrow & 7);
  const uint16_t* abase = a  + (size_t)(m0 + lrow) * 3072 + kz * 1536 + gch * 8;
  const uint16_t* bbase = wt + (size_t)(n0 + lrow) * 3072 + kz * 1536 + gch * 8;

  f32x4 acc[4][4];
#pragma unroll
  for(int mt = 0; mt < 4; ++mt)
#pragma unroll
    for(int nt = 0; nt < 4; ++nt) acc[mt][nt] = fzero();

  for(int kt = 0; kt < 24; ++kt){
    __syncthreads();
#pragma unroll
    for(int it = 0; it < 4; ++it){
      int seg = it * 4 + wave;
      gl2lds16(abase + (size_t)seg * 24576 + kt * 64, as + seg * 512);
      gl2lds16(bbase + (size_t)seg * 24576 + kt * 64, bs + seg * 512);
    }
    __syncthreads();
#pragma unroll
    for(int ks2 = 0; ks2 < 2; ++ks2){
      bf16x8 af[4], bfr[4];
#pragma unroll
      for(int mt = 0; mt < 4; ++mt){
        int row = mo + mt * 16 + ml;
        af[mt] = load_frag(as + row * 64 + (((ks2 * 4 + qd) ^ (row & 7)) * 8));
      }
#pragma unroll
      for(int nt = 0; nt < 4; ++nt){
        int row = no + nt * 16 + ml;
        bfr[nt] = load_frag(bs + row * 64 + (((ks2 * 4 + qd) ^ (row & 7)) * 8));
      }
#pragma unroll
      for(int mt = 0; mt < 4; ++mt)
#pragma unroll
        for(int nt = 0; nt < 4; ++nt)
          acc[mt][nt] = MFMA16x16(af[mt], bfr[nt], acc[mt][nt]);
    }
  }

  float* dst = part + (size_t)kz * 4096 * 1024;
#pragma unroll
  for(int mt = 0; mt < 4; ++mt)
#pragma unroll
    for(int nt = 0; nt < 4; ++nt)
#pragma unroll
      for(int r = 0; r < 4; ++r){
        int row = m0 + mo + mt * 16 + qd * 4 + r;
        int col = n0 + no + nt * 16 + ml;
        dst[(size_t)row * 1024 + col] = acc[mt][nt][r];
      }
}

// out = part0 + part1 (float4)
__global__ __launch_bounds__(256) void k_addout(const float* __restrict__ part,
                                                float* __restrict__ out){
  int i = blockIdx.x * 256 + threadIdx.x;
  const float4* p0 = (const float4*)part;
  const float4* p1 = p0 + (size_t)1048576;
  float4 a = p0[i], b = p1[i];
  float4 c; c.x = a.x + b.x; c.y = a.y + b.y; c.z = a.z + b.z; c.w = a.w + b.w;
  ((float4*)out)[i] = c;
}

// ---------------- launch ----------------

extern "C" void kernel_launch(void* const* d_in, const int* in_sizes, int n_in,
                              void* d_out, int out_size, void* d_ws, size_t ws_size,
                              hipStream_t stream) {
  (void)in_sizes; (void)n_in; (void)out_size; (void)ws_size;
  const float* x      = (const float*)d_in[0];
  const float* w_down = (const float*)d_in[2];
  const float* rms_w  = (const float*)d_in[3];
  const float* w_up   = (const float*)d_in[4];
  const float* w_o    = (const float*)d_in[5];
  float* out = (float*)d_out;

  char* ws = (char*)d_ws;
  uint16_t* h_bf   = (uint16_t*)(ws);                     // 1,572,864 B
  uint16_t* w_up_t = (uint16_t*)(ws + 1572864);           // 3,538,944 B
  uint16_t* w_o_t  = (uint16_t*)(ws + 5111808);           // 6,291,456 B
  uint16_t* w_dn_t = (uint16_t*)(ws + 11403264);          //   393,216 B
  uint16_t* q_tb   = (uint16_t*)(ws + 11796480);          // 25,165,824 B
  uint16_t* k_tb   = (uint16_t*)(ws + 36962304);          // 25,165,824 B
  uint16_t* v_tb   = (uint16_t*)(ws + 62128128);          // 25,165,824 B
  uint16_t* attnO  = (uint16_t*)(ws + 87293952);          // 25,165,824 B
  float*    part   = (float*)(ws + 11796480);             // alias q_tb/k_tb (dead after attn)

  k_transpose_cvt<<<dim3(288, 6), 256, 0, stream>>>(w_up, w_up_t, 192, 9216);
  k_transpose_cvt<<<dim3(32, 96), 256, 0, stream>>>(w_o,  w_o_t,  3072, 1024);
  k_transpose_cvt<<<dim3(6, 32),  256, 0, stream>>>(w_down, w_dn_t, 1024, 192);
  k_down_mfma<<<128, 256, 0, stream>>>(x, w_dn_t, rms_w, h_bf);
  k_gemm_up<<<dim3(18, 128), 256, 0, stream>>>(h_bf, w_up_t, q_tb, k_tb, v_tb);
  k_attn<<<512, 256, 0, stream>>>(q_tb, k_tb, v_tb, attnO);
  k_gemm_o_tile<<<dim3(8, 32, 2), 256, 0, stream>>>(attnO, w_o_t, part);
  k_addout<<<4096, 256, 0, stream>>>(part, out);
}

// Round 6
// 370.479 us; speedup vs baseline: 1.0125x; 1.0125x over previous
//
#include <hip/hip_runtime.h>
#include <stdint.h>
#include <stddef.h>

// ---------------- common helpers ----------------

typedef __bf16 bf16x8 __attribute__((ext_vector_type(8)));
typedef float  f32x4  __attribute__((ext_vector_type(4)));

#define MFMA16x16(a,b,c) __builtin_amdgcn_mfma_f32_16x16x32_bf16((a),(b),(c),0,0,0)

__device__ __forceinline__ uint16_t f2bf(float f){
  union { float f; uint32_t u; } v; v.f = f;
  uint32_t u = v.u + 0x7fffu + ((v.u >> 16) & 1u);
  return (uint16_t)(u >> 16);
}
__device__ __forceinline__ bf16x8 load_frag(const uint16_t* p){
  uint4 u = *reinterpret_cast<const uint4*>(p);
  return __builtin_bit_cast(bf16x8, u);
}
__device__ __forceinline__ f32x4 fzero(){
  f32x4 z = {0.f, 0.f, 0.f, 0.f};
  return z;
}
__device__ __forceinline__ uint32_t pack2(float a, float b){
  return (uint32_t)f2bf(a) | ((uint32_t)f2bf(b) << 16);
}
// async global->LDS DMA, 16B per lane, LDS dst = wave-uniform base + lane*16
__device__ __forceinline__ void gl2lds16(const uint16_t* g, uint16_t* l){
  __builtin_amdgcn_global_load_lds(
      (const __attribute__((address_space(1))) uint32_t*)g,
      (__attribute__((address_space(3))) uint32_t*)l,
      16, 0, 0);
}

// ---------------- 1) transpose + f32->bf16 convert ----------------
__global__ __launch_bounds__(256) void k_transpose_cvt(const float* __restrict__ in,
                                                       uint16_t* __restrict__ out,
                                                       int R, int C){
  __shared__ float t[32][33];
  const int tc = blockIdx.x * 32;
  const int tr = blockIdx.y * 32;
  const int j = threadIdx.x & 31, i0 = threadIdx.x >> 5;
  for(int ii = 0; ii < 4; ++ii){
    int r = i0 + ii * 8;
    t[r][j] = in[(size_t)(tr + r) * C + tc + j];
  }
  __syncthreads();
  for(int ii = 0; ii < 4; ++ii){
    int c = i0 + ii * 8;
    out[(size_t)(tc + c) * R + tr + j] = f2bf(t[j][c]);
  }
}

// ---------------- 2) down-proj + RMSNorm via MFMA ----------------
__global__ __launch_bounds__(256) void k_down_mfma(const float* __restrict__ x,
                                                   const uint16_t* __restrict__ wdt,
                                                   const float* __restrict__ rms_w,
                                                   uint16_t* __restrict__ h_out){
  __shared__ __align__(16) uint16_t as[32 * 64];
  __shared__ float hsq[32];
  const int tid  = threadIdx.x;
  const int wave = tid >> 6, lane = tid & 63;
  const int ml = lane & 15, qd = lane >> 4;
  const int m0 = blockIdx.x * 32;
  const int n0w = wave * 48;
  if(tid < 32) hsq[tid] = 0.f;

  f32x4 acc[2][3];
#pragma unroll
  for(int mt = 0; mt < 2; ++mt)
#pragma unroll
    for(int nt = 0; nt < 3; ++nt) acc[mt][nt] = fzero();

  const int srow = tid >> 3, sc = tid & 7;
  for(int kt = 0; kt < 16; ++kt){
    const float* src = x + (size_t)(m0 + srow) * 1024 + kt * 64 + sc * 8;
    float4 a = *reinterpret_cast<const float4*>(src);
    float4 b = *reinterpret_cast<const float4*>(src + 4);
    uint4 pk;
    pk.x = pack2(a.x, a.y); pk.y = pack2(a.z, a.w);
    pk.z = pack2(b.x, b.y); pk.w = pack2(b.z, b.w);
    __syncthreads();
    *reinterpret_cast<uint4*>(as + srow * 64 + ((sc ^ (srow & 7)) * 8)) = pk;
    __syncthreads();
#pragma unroll
    for(int kk = 0; kk < 2; ++kk){
      bf16x8 af[2];
#pragma unroll
      for(int mt = 0; mt < 2; ++mt){
        int row = mt * 16 + ml;
        af[mt] = load_frag(as + row * 64 + (((kk * 4 + qd) ^ (row & 7)) * 8));
      }
#pragma unroll
      for(int nt = 0; nt < 3; ++nt){
        bf16x8 bfr = load_frag(wdt + (size_t)(n0w + nt * 16 + ml) * 1024 + kt * 64 + kk * 32 + qd * 8);
#pragma unroll
        for(int mt = 0; mt < 2; ++mt)
          acc[mt][nt] = MFMA16x16(af[mt], bfr, acc[mt][nt]);
      }
    }
  }
  __syncthreads();
#pragma unroll
  for(int mt = 0; mt < 2; ++mt)
#pragma unroll
    for(int r = 0; r < 4; ++r){
      float s = acc[mt][0][r]*acc[mt][0][r] + acc[mt][1][r]*acc[mt][1][r] + acc[mt][2][r]*acc[mt][2][r];
#pragma unroll
      for(int off = 1; off < 16; off <<= 1) s += __shfl_xor(s, off);
      if(ml == 0) atomicAdd(&hsq[mt * 16 + qd * 4 + r], s);
    }
  __syncthreads();
  float rw[3];
#pragma unroll
  for(int nt = 0; nt < 3; ++nt) rw[nt] = rms_w[n0w + nt * 16 + ml];
#pragma unroll
  for(int mt = 0; mt < 2; ++mt)
#pragma unroll
    for(int r = 0; r < 4; ++r){
      int row = mt * 16 + qd * 4 + r;
      float scl = rsqrtf(hsq[row] * (1.0f / 192.0f) + 1e-6f);
#pragma unroll
      for(int nt = 0; nt < 3; ++nt)
        h_out[(size_t)(m0 + row) * 192 + n0w + nt * 16 + ml] = f2bf(acc[mt][nt][r] * scl * rw[nt]);
    }
}

// ---------------- 3) up-proj GEMM v2: LDS repack -> full-line stores --------
__global__ __launch_bounds__(256) void k_gemm_up(const uint16_t* __restrict__ hmat,
                                                 const uint16_t* __restrict__ wt,
                                                 uint16_t* __restrict__ q_t,
                                                 uint16_t* __restrict__ k_t,
                                                 uint16_t* __restrict__ v_t){
  __shared__ __align__(16) uint16_t rp[16 * 129 * 8];   // 33,024 B
  const int wave = threadIdx.x >> 6, lane = threadIdx.x & 63;
  const int ml = lane & 15, qd = lane >> 4;
  const int m0 = blockIdx.y * 32;
  const int bx = blockIdx.x;
  const int which = bx / 6;                // 0=q 1=k 2=v
  const int d0b = (bx % 6) * 32;
  const int n0w = bx * 512 + wave * 128;
  const int d0w = d0b + wave * 8;

  bf16x8 af[2][6];
#pragma unroll
  for(int mt = 0; mt < 2; ++mt)
#pragma unroll
    for(int kk = 0; kk < 6; ++kk)
      af[mt][kk] = load_frag(hmat + (size_t)(m0 + mt * 16 + ml) * 192 + kk * 32 + qd * 8);

  f32x4 acc[8][2];
#pragma unroll
  for(int nt = 0; nt < 8; ++nt){ acc[nt][0] = fzero(); acc[nt][1] = fzero(); }
#pragma unroll
  for(int nt = 0; nt < 8; ++nt){
#pragma unroll
    for(int kk = 0; kk < 6; ++kk){
      bf16x8 b = load_frag(wt + (size_t)(n0w + nt * 16 + ml) * 192 + kk * 32 + qd * 8);
      acc[nt][0] = MFMA16x16(af[0][kk], b, acc[nt][0]);
      acc[nt][1] = MFMA16x16(af[1][kk], b, acc[nt][1]);
    }
  }

  const int b   = m0 >> 11;
  const int s0  = m0 & 2047;
  const int kt2 = s0 >> 6;
  const int row0 = s0 & 63;                // 32-aligned: rs bits come from t
  uint4* rp4 = (uint4*)rp;

  if(which < 2){
    const float qs = which ? 1.0f : 0.07216878364870322f;   // fold 1/sqrt(192) into Q
    const bool rope = (d0w >= 128) && (d0w < 160);
#pragma unroll
    for(int mt = 0; mt < 2; ++mt)
#pragma unroll
      for(int r = 0; r < 4; ++r){
        int t = mt * 16 + qd * 4 + r;
        int s = s0 + t;
        float v[8];
#pragma unroll
        for(int nt = 0; nt < 8; ++nt) v[nt] = acc[nt][mt][r] * qs;
        if(rope){
#pragma unroll
          for(int pi = 0; pi < 4; ++pi){
            int fi = (d0w + 2 * pi - 128) >> 1;
            float invf = __expf(-(float)fi * 0.5756462732485114f); // ln(10000)/16
            float sn, cs;
            sincosf((float)s * invf, &sn, &cs);
            float e = v[2 * pi], o = v[2 * pi + 1];
            v[2 * pi]     = e * cs - o * sn;
            v[2 * pi + 1] = o * cs + e * sn;
          }
        }
        uint4 pk;
        pk.x = pack2(v[0], v[1]); pk.y = pack2(v[2], v[3]);
        pk.z = pack2(v[4], v[5]); pk.w = pack2(v[6], v[7]);
        rp4[ml * 129 + t * 4 + (wave ^ (t & 3))] = pk;
      }
  } else {
#pragma unroll
    for(int nt = 0; nt < 8; ++nt){
      int dl = wave * 8 + nt;
#pragma unroll
      for(int mt = 0; mt < 2; ++mt){
        int jc = mt * 2 + (qd >> 1);
        int slot = ml * 129 + dl * 4 + (jc ^ (dl & 3));
        uint2 pk;
        pk.x = pack2(acc[nt][mt][0], acc[nt][mt][1]);
        pk.y = pack2(acc[nt][mt][2], acc[nt][mt][3]);
        *(reinterpret_cast<uint2*>(rp + slot * 8) + (qd & 1)) = pk;
      }
    }
  }
  __syncthreads();

  if(which < 2){
    uint16_t* dst = which ? k_t : q_t;
    const int cb = d0b >> 3;
#pragma unroll
    for(int it = 0; it < 8; ++it){
      int h = wave * 4 + (it & 3), rhalf = it >> 2;
      int tloc = rhalf * 16 + (lane >> 2), p = lane & 3;
      int row = row0 + tloc;
      uint4 val = rp4[h * 129 + tloc * 4 + p];
      size_t off = ((size_t)(b * 16 + h) * 32 + kt2) * 12288
                 + (size_t)row * 192 + ((cb ^ (tloc & 4)) + p) * 8;
      *reinterpret_cast<uint4*>(dst + off) = val;
    }
  } else {
    const int cs0 = row0 >> 3;
#pragma unroll
    for(int it = 0; it < 8; ++it){
      int h = wave * 4 + (it & 3), dhalf = it >> 2;
      int dl = dhalf * 16 + (lane >> 2), p = lane & 3;
      uint4 val = rp4[h * 129 + dl * 4 + p];
      size_t off = ((size_t)(b * 16 + h) * 32 + kt2) * 12288
                 + (size_t)(d0b + dl) * 64 + ((cs0 ^ (dl & 4)) + p) * 8;
      *reinterpret_cast<uint4*>(v_t + off) = val;
    }
  }
}

// ---------------- 4) causal flash attention v8 ----------------
// = R4's 2-q-tile kernel (correctness-proven formulas) restructured for
// 2-blocks/CU co-residency: single KV buffer, LDS 35,840 B (2x = 71,680,
// under the ~102KB scheduling pool inferred from R0-R4 occupancy data).
// 512 blocks x 256 thr; wave owns 2 q-tiles -> each K/V ds_read feeds 2
// MFMAs (27 reads / 50 MFMA per iter, half of the 1-tile variants that all
// plateaued at 21-25% MfmaUtil). Stage(kt+1) issued right after barrier [B];
// the vmcnt(0) stall at the next iter top is covered by the co-resident
// partner block (m114 cross-block overlap).
__global__ __launch_bounds__(256, 2) void k_attn(const uint16_t* __restrict__ q_t,
                                                 const uint16_t* __restrict__ k_t,
                                                 const uint16_t* __restrict__ v_t,
                                                 uint16_t* __restrict__ attn_out){
  // carve (elems): kb[6144] vb[6656 incl ones rows] psw[4*1280] = 17,920
  __shared__ __align__(16) uint16_t smem[17920];
  const int tid  = threadIdx.x;
  const int wave = tid >> 6;
  const int lane = tid & 63;
  const int ml   = lane & 15;
  const int qd   = lane >> 4;
  const int bx   = blockIdx.x;
  const int bh   = bx & 31;
  const int qb   = (bx < 256) ? (15 - (bx >> 5)) : ((bx >> 5) - 8);
  const int last = 4 * qb + 3;

  uint16_t* const kb  = smem;                 // 32 x 192      (12,288 B)
  uint16_t* const vb  = smem + 6144;          // 208 x 32-key  (13,312 B, rows 192.. = ones)
  uint16_t* const psw = smem + 12800 + wave * 1280;   // [32][40] per wave

  const uint16_t* kbase = k_t + (size_t)bh * 393216;
  const uint16_t* vbase = v_t + (size_t)bh * 393216;
  const int hh = bh & 15, bb = bh >> 4;

  // V gather constants (verified R3/R4): lane L of seg g fills LDS elems
  // g*512+L*8; source elem = d*64 + (((h*4+c)^(d&7))*8).
  const int c_  = (lane & 3) ^ ((lane >> 3) & 3);
  const int s7_ = (lane >> 2) & 7;
  const int vg_ = (lane >> 2) * 64;
  const int voff0 = vg_ + ((c_ ^ s7_) * 8);
  const int voff1 = vg_ + (((4 + c_) ^ s7_) * 8);
  // PV read base: addr = vb + dt*512 + vpo (verified R3/R4)
  const int vpo = ml * 32 + ((qd ^ ((ml >> 1) & 3)) * 8);

  // ---- Q fragments: direct global->regs, 2 q-tiles x 6 kk ----
  bf16x8 qf[2][6];
  {
    const int row = wave * 16 + ml;
    const int sw = row & 7;
#pragma unroll
    for(int t = 0; t < 2; ++t){
      const uint16_t* qtb = q_t + ((size_t)bh * 32 + qb * 2 + t) * 12288 + (size_t)row * 192;
#pragma unroll
      for(int kk = 0; kk < 6; ++kk)
        qf[t][kk] = load_frag(qtb + (((kk * 4 + qd) ^ sw) * 8));
    }
  }

  // ones rows (vb elems 6144..6655 = d-rows 192..207): denominator source;
  // persist for the whole kernel (K/V staging only touches rows 0..191).
  ((uint32_t*)(vb + 6144))[tid] = 0x3F803F80u;

  // stage KV tile kt (32 keys): 3 K + 3 V DMAs per wave
  auto stageKV = [&](int kt){
    const uint16_t* ksrc = kbase + (size_t)(kt >> 1) * 12288 + (kt & 1) * 6144
                         + wave * 1536 + lane * 8;
    uint16_t* kd = kb + wave * 1536;
    gl2lds16(ksrc,        kd);
    gl2lds16(ksrc + 512,  kd + 512);
    gl2lds16(ksrc + 1024, kd + 1024);
    const int vo = (kt & 1) ? voff1 : voff0;
    const uint16_t* vsrc = vbase + (size_t)(kt >> 1) * 12288 + (size_t)(wave * 3) * 1024 + vo;
    uint16_t* vd = vb + wave * 1536;
    gl2lds16(vsrc,        vd);
    gl2lds16(vsrc + 1024, vd + 512);
    gl2lds16(vsrc + 2048, vd + 1024);
  };

  stageKV(0);
  asm volatile("s_waitcnt lgkmcnt(0)" ::: "memory");   // own ones-writes drained

  f32x4 o[2][13];
#pragma unroll
  for(int t = 0; t < 2; ++t)
#pragma unroll
    for(int i = 0; i < 13; ++i) o[t][i] = fzero();

  const int r0 = qb * 128 + wave * 16;       // tile-0 first q-row
  const int r1 = r0 + 64;                    // tile-1 first q-row
  for(int kt = 0; kt <= last; ++kt){
    __builtin_amdgcn_sched_barrier(0);
    asm volatile("s_waitcnt vmcnt(0)" ::: "memory");   // tile kt landed (own DMAs)
    __builtin_amdgcn_sched_barrier(0);
    __builtin_amdgcn_s_barrier();            // [A] tile kt staged everywhere

    const int kl = kt * 32;
    if(kl <= r1 + 15){                       // wave has work this tile
      const bool a0 = (kl <= r0 + 15);       // tile-0 active (uniform)

      f32x4 s[2][2];
      s[0][0] = fzero(); s[0][1] = fzero(); s[1][0] = fzero(); s[1][1] = fzero();
      __builtin_amdgcn_s_setprio(1);
#pragma unroll
      for(int nt = 0; nt < 2; ++nt){
        int row = nt * 16 + ml;
#pragma unroll
        for(int kk = 0; kk < 6; ++kk){
          bf16x8 bfr = load_frag(kb + row * 192 + (((kk * 4 + qd) ^ (row & 7)) * 8));
          if(a0) s[0][nt] = MFMA16x16(qf[0][kk], bfr, s[0][nt]);
          s[1][nt] = MFMA16x16(qf[1][kk], bfr, s[1][nt]);
        }
      }
      __builtin_amdgcn_s_setprio(0);

#pragma unroll
      for(int t = 0; t < 2; ++t){
        if(t == 0 && !a0) continue;
        const int rq = t ? r1 : r0;
        const bool diag = (kl + 31 > rq);
#pragma unroll
        for(int nt = 0; nt < 2; ++nt)
#pragma unroll
          for(int r = 0; r < 4; ++r){
            float v = s[t][nt][r];
            if(diag){
              int i = rq + qd * 4 + r;
              int j = kl + nt * 16 + ml;
              if(j > i) v = -1e9f;
            }
            psw[(t * 16 + qd * 4 + r) * 40 + nt * 16 + ml] = f2bf(__expf(v));
          }
      }
      bf16x8 pa0 = load_frag(psw + ml * 40 + qd * 8);
      bf16x8 pa1 = load_frag(psw + (16 + ml) * 40 + qd * 8);
      __builtin_amdgcn_s_setprio(1);
#pragma unroll
      for(int dt = 0; dt < 13; ++dt){
        bf16x8 vbf = load_frag(vb + dt * 512 + vpo);
        if(a0) o[0][dt] = MFMA16x16(pa0, vbf, o[0][dt]);
        o[1][dt] = MFMA16x16(pa1, vbf, o[1][dt]);
      }
      __builtin_amdgcn_s_setprio(0);
    }
    __builtin_amdgcn_s_barrier();            // [B] all reads of tile kt done
    if(kt < last) stageKV(kt + 1);           // overlap with partner block
  }

  // ---- epilogue: 2 q-tiles x 16 rows per wave ----
#pragma unroll
  for(int t = 0; t < 2; ++t){
    const int rq = t ? r1 : r0;
#pragma unroll
    for(int r = 0; r < 4; ++r){
      int i = rq + qd * 4 + r;
      float inv = 1.0f / o[t][12][r];
      size_t obase = ((size_t)bb * 2048 + i) * 3072 + hh * 192;
#pragma unroll
      for(int dt = 0; dt < 12; ++dt)
        attn_out[obase + dt * 16 + ml] = f2bf(o[t][dt][r] * inv);
    }
  }
}

// ---------------- 5) out-proj GEMM: m97-style LDS-tiled, split-K=2 ----------
__global__ __launch_bounds__(256) void k_gemm_o_tile(const uint16_t* __restrict__ a,
                                                     const uint16_t* __restrict__ wt,
                                                     float* __restrict__ part){
  __shared__ __align__(16) uint16_t as[128 * 64];
  __shared__ __align__(16) uint16_t bs[128 * 64];
  const int wave = threadIdx.x >> 6, lane = threadIdx.x & 63;
  const int ml = lane & 15, qd = lane >> 4;
  const int m0 = blockIdx.y * 128, n0 = blockIdx.x * 128;
  const int kz = blockIdx.z;
  const int mo = (wave >> 1) * 64, no = (wave & 1) * 64;

  const int lrow = lane >> 3;
  const int gch  = (lane & 7) ^ (lrow & 7);
  const uint16_t* abase = a  + (size_t)(m0 + lrow) * 3072 + kz * 1536 + gch * 8;
  const uint16_t* bbase = wt + (size_t)(n0 + lrow) * 3072 + kz * 1536 + gch * 8;

  f32x4 acc[4][4];
#pragma unroll
  for(int mt = 0; mt < 4; ++mt)
#pragma unroll
    for(int nt = 0; nt < 4; ++nt) acc[mt][nt] = fzero();

  for(int kt = 0; kt < 24; ++kt){
    __syncthreads();
#pragma unroll
    for(int it = 0; it < 4; ++it){
      int seg = it * 4 + wave;
      gl2lds16(abase + (size_t)seg * 24576 + kt * 64, as + seg * 512);
      gl2lds16(bbase + (size_t)seg * 24576 + kt * 64, bs + seg * 512);
    }
    __syncthreads();
#pragma unroll
    for(int ks2 = 0; ks2 < 2; ++ks2){
      bf16x8 af[4], bfr[4];
#pragma unroll
      for(int mt = 0; mt < 4; ++mt){
        int row = mo + mt * 16 + ml;
        af[mt] = load_frag(as + row * 64 + (((ks2 * 4 + qd) ^ (row & 7)) * 8));
      }
#pragma unroll
      for(int nt = 0; nt < 4; ++nt){
        int row = no + nt * 16 + ml;
        bfr[nt] = load_frag(bs + row * 64 + (((ks2 * 4 + qd) ^ (row & 7)) * 8));
      }
#pragma unroll
      for(int mt = 0; mt < 4; ++mt)
#pragma unroll
        for(int nt = 0; nt < 4; ++nt)
          acc[mt][nt] = MFMA16x16(af[mt], bfr[nt], acc[mt][nt]);
    }
  }

  float* dst = part + (size_t)kz * 4096 * 1024;
#pragma unroll
  for(int mt = 0; mt < 4; ++mt)
#pragma unroll
    for(int nt = 0; nt < 4; ++nt)
#pragma unroll
      for(int r = 0; r < 4; ++r){
        int row = m0 + mo + mt * 16 + qd * 4 + r;
        int col = n0 + no + nt * 16 + ml;
        dst[(size_t)row * 1024 + col] = acc[mt][nt][r];
      }
}

// out = part0 + part1 (float4)
__global__ __launch_bounds__(256) void k_addout(const float* __restrict__ part,
                                                float* __restrict__ out){
  int i = blockIdx.x * 256 + threadIdx.x;
  const float4* p0 = (const float4*)part;
  const float4* p1 = p0 + (size_t)1048576;
  float4 a = p0[i], b = p1[i];
  float4 c; c.x = a.x + b.x; c.y = a.y + b.y; c.z = a.z + b.z; c.w = a.w + b.w;
  ((float4*)out)[i] = c;
}

// ---------------- launch ----------------

extern "C" void kernel_launch(void* const* d_in, const int* in_sizes, int n_in,
                              void* d_out, int out_size, void* d_ws, size_t ws_size,
                              hipStream_t stream) {
  (void)in_sizes; (void)n_in; (void)out_size; (void)ws_size;
  const float* x      = (const float*)d_in[0];
  const float* w_down = (const float*)d_in[2];
  const float* rms_w  = (const float*)d_in[3];
  const float* w_up   = (const float*)d_in[4];
  const float* w_o    = (const float*)d_in[5];
  float* out = (float*)d_out;

  char* ws = (char*)d_ws;
  uint16_t* h_bf   = (uint16_t*)(ws);                     // 1,572,864 B
  uint16_t* w_up_t = (uint16_t*)(ws + 1572864);           // 3,538,944 B
  uint16_t* w_o_t  = (uint16_t*)(ws + 5111808);           // 6,291,456 B
  uint16_t* w_dn_t = (uint16_t*)(ws + 11403264);          //   393,216 B
  uint16_t* q_tb   = (uint16_t*)(ws + 11796480);          // 25,165,824 B
  uint16_t* k_tb   = (uint16_t*)(ws + 36962304);          // 25,165,824 B
  uint16_t* v_tb   = (uint16_t*)(ws + 62128128);          // 25,165,824 B
  uint16_t* attnO  = (uint16_t*)(ws + 87293952);          // 25,165,824 B
  float*    part   = (float*)(ws + 11796480);             // alias q_tb/k_tb (dead after attn)

  k_transpose_cvt<<<dim3(288, 6), 256, 0, stream>>>(w_up, w_up_t, 192, 9216);
  k_transpose_cvt<<<dim3(32, 96), 256, 0, stream>>>(w_o,  w_o_t,  3072, 1024);
  k_transpose_cvt<<<dim3(6, 32),  256, 0, stream>>>(w_down, w_dn_t, 1024, 192);
  k_down_mfma<<<128, 256, 0, stream>>>(x, w_dn_t, rms_w, h_bf);
  k_gemm_up<<<dim3(18, 128), 256, 0, stream>>>(h_bf, w_up_t, q_tb, k_tb, v_tb);
  k_attn<<<512, 256, 0, stream>>>(q_tb, k_tb, v_tb, attnO);
  k_gemm_o_tile<<<dim3(8, 32, 2), 256, 0, stream>>>(attnO, w_o_t, part);
  k_addout<<<4096, 256, 0, stream>>>(part, out);
}

// Round 7
// 342.920 us; speedup vs baseline: 1.0938x; 1.0804x over previous
//
#include <hip/hip_runtime.h>
#include <stdint.h>
#include <stddef.h>

// ---------------- common helpers ----------------

typedef __bf16 bf16x8 __attribute__((ext_vector_type(8)));
typedef float  f32x4  __attribute__((ext_vector_type(4)));

#define MFMA16x16(a,b,c) __builtin_amdgcn_mfma_f32_16x16x32_bf16((a),(b),(c),0,0,0)

__device__ __forceinline__ uint16_t f2bf(float f){
  union { float f; uint32_t u; } v; v.f = f;
  uint32_t u = v.u + 0x7fffu + ((v.u >> 16) & 1u);
  return (uint16_t)(u >> 16);
}
__device__ __forceinline__ bf16x8 load_frag(const uint16_t* p){
  uint4 u = *reinterpret_cast<const uint4*>(p);
  return __builtin_bit_cast(bf16x8, u);
}
__device__ __forceinline__ f32x4 fzero(){
  f32x4 z = {0.f, 0.f, 0.f, 0.f};
  return z;
}
__device__ __forceinline__ uint32_t pack2(float a, float b){
  return (uint32_t)f2bf(a) | ((uint32_t)f2bf(b) << 16);
}
// async global->LDS DMA, 16B per lane, LDS dst = wave-uniform base + lane*16
__device__ __forceinline__ void gl2lds16(const uint16_t* g, uint16_t* l){
  __builtin_amdgcn_global_load_lds(
      (const __attribute__((address_space(1))) uint32_t*)g,
      (__attribute__((address_space(3))) uint32_t*)l,
      16, 0, 0);
}

// ---------------- 1) transpose + f32->bf16 convert ----------------
__global__ __launch_bounds__(256) void k_transpose_cvt(const float* __restrict__ in,
                                                       uint16_t* __restrict__ out,
                                                       int R, int C){
  __shared__ float t[32][33];
  const int tc = blockIdx.x * 32;
  const int tr = blockIdx.y * 32;
  const int j = threadIdx.x & 31, i0 = threadIdx.x >> 5;
  for(int ii = 0; ii < 4; ++ii){
    int r = i0 + ii * 8;
    t[r][j] = in[(size_t)(tr + r) * C + tc + j];
  }
  __syncthreads();
  for(int ii = 0; ii < 4; ++ii){
    int c = i0 + ii * 8;
    out[(size_t)(tc + c) * R + tr + j] = f2bf(t[j][c]);
  }
}

// ---------------- 2) down-proj + RMSNorm via MFMA ----------------
__global__ __launch_bounds__(256) void k_down_mfma(const float* __restrict__ x,
                                                   const uint16_t* __restrict__ wdt,
                                                   const float* __restrict__ rms_w,
                                                   uint16_t* __restrict__ h_out){
  __shared__ __align__(16) uint16_t as[32 * 64];
  __shared__ float hsq[32];
  const int tid  = threadIdx.x;
  const int wave = tid >> 6, lane = tid & 63;
  const int ml = lane & 15, qd = lane >> 4;
  const int m0 = blockIdx.x * 32;
  const int n0w = wave * 48;
  if(tid < 32) hsq[tid] = 0.f;

  f32x4 acc[2][3];
#pragma unroll
  for(int mt = 0; mt < 2; ++mt)
#pragma unroll
    for(int nt = 0; nt < 3; ++nt) acc[mt][nt] = fzero();

  const int srow = tid >> 3, sc = tid & 7;
  for(int kt = 0; kt < 16; ++kt){
    const float* src = x + (size_t)(m0 + srow) * 1024 + kt * 64 + sc * 8;
    float4 a = *reinterpret_cast<const float4*>(src);
    float4 b = *reinterpret_cast<const float4*>(src + 4);
    uint4 pk;
    pk.x = pack2(a.x, a.y); pk.y = pack2(a.z, a.w);
    pk.z = pack2(b.x, b.y); pk.w = pack2(b.z, b.w);
    __syncthreads();
    *reinterpret_cast<uint4*>(as + srow * 64 + ((sc ^ (srow & 7)) * 8)) = pk;
    __syncthreads();
#pragma unroll
    for(int kk = 0; kk < 2; ++kk){
      bf16x8 af[2];
#pragma unroll
      for(int mt = 0; mt < 2; ++mt){
        int row = mt * 16 + ml;
        af[mt] = load_frag(as + row * 64 + (((kk * 4 + qd) ^ (row & 7)) * 8));
      }
#pragma unroll
      for(int nt = 0; nt < 3; ++nt){
        bf16x8 bfr = load_frag(wdt + (size_t)(n0w + nt * 16 + ml) * 1024 + kt * 64 + kk * 32 + qd * 8);
#pragma unroll
        for(int mt = 0; mt < 2; ++mt)
          acc[mt][nt] = MFMA16x16(af[mt], bfr, acc[mt][nt]);
      }
    }
  }
  __syncthreads();
#pragma unroll
  for(int mt = 0; mt < 2; ++mt)
#pragma unroll
    for(int r = 0; r < 4; ++r){
      float s = acc[mt][0][r]*acc[mt][0][r] + acc[mt][1][r]*acc[mt][1][r] + acc[mt][2][r]*acc[mt][2][r];
#pragma unroll
      for(int off = 1; off < 16; off <<= 1) s += __shfl_xor(s, off);
      if(ml == 0) atomicAdd(&hsq[mt * 16 + qd * 4 + r], s);
    }
  __syncthreads();
  float rw[3];
#pragma unroll
  for(int nt = 0; nt < 3; ++nt) rw[nt] = rms_w[n0w + nt * 16 + ml];
#pragma unroll
  for(int mt = 0; mt < 2; ++mt)
#pragma unroll
    for(int r = 0; r < 4; ++r){
      int row = mt * 16 + qd * 4 + r;
      float scl = rsqrtf(hsq[row] * (1.0f / 192.0f) + 1e-6f);
#pragma unroll
      for(int nt = 0; nt < 3; ++nt)
        h_out[(size_t)(m0 + row) * 192 + n0w + nt * 16 + ml] = f2bf(acc[mt][nt][r] * scl * rw[nt]);
    }
}

// ---------------- 3) up-proj GEMM v2: LDS repack -> full-line stores --------
__global__ __launch_bounds__(256) void k_gemm_up(const uint16_t* __restrict__ hmat,
                                                 const uint16_t* __restrict__ wt,
                                                 uint16_t* __restrict__ q_t,
                                                 uint16_t* __restrict__ k_t,
                                                 uint16_t* __restrict__ v_t){
  __shared__ __align__(16) uint16_t rp[16 * 129 * 8];   // 33,024 B
  const int wave = threadIdx.x >> 6, lane = threadIdx.x & 63;
  const int ml = lane & 15, qd = lane >> 4;
  const int m0 = blockIdx.y * 32;
  const int bx = blockIdx.x;
  const int which = bx / 6;                // 0=q 1=k 2=v
  const int d0b = (bx % 6) * 32;
  const int n0w = bx * 512 + wave * 128;
  const int d0w = d0b + wave * 8;

  bf16x8 af[2][6];
#pragma unroll
  for(int mt = 0; mt < 2; ++mt)
#pragma unroll
    for(int kk = 0; kk < 6; ++kk)
      af[mt][kk] = load_frag(hmat + (size_t)(m0 + mt * 16 + ml) * 192 + kk * 32 + qd * 8);

  f32x4 acc[8][2];
#pragma unroll
  for(int nt = 0; nt < 8; ++nt){ acc[nt][0] = fzero(); acc[nt][1] = fzero(); }
#pragma unroll
  for(int nt = 0; nt < 8; ++nt){
#pragma unroll
    for(int kk = 0; kk < 6; ++kk){
      bf16x8 b = load_frag(wt + (size_t)(n0w + nt * 16 + ml) * 192 + kk * 32 + qd * 8);
      acc[nt][0] = MFMA16x16(af[0][kk], b, acc[nt][0]);
      acc[nt][1] = MFMA16x16(af[1][kk], b, acc[nt][1]);
    }
  }

  const int b   = m0 >> 11;
  const int s0  = m0 & 2047;
  const int kt2 = s0 >> 6;
  const int row0 = s0 & 63;                // 32-aligned: rs bits come from t
  uint4* rp4 = (uint4*)rp;

  if(which < 2){
    const float qs = which ? 1.0f : 0.07216878364870322f;   // fold 1/sqrt(192) into Q
    const bool rope = (d0w >= 128) && (d0w < 160);
#pragma unroll
    for(int mt = 0; mt < 2; ++mt)
#pragma unroll
      for(int r = 0; r < 4; ++r){
        int t = mt * 16 + qd * 4 + r;
        int s = s0 + t;
        float v[8];
#pragma unroll
        for(int nt = 0; nt < 8; ++nt) v[nt] = acc[nt][mt][r] * qs;
        if(rope){
#pragma unroll
          for(int pi = 0; pi < 4; ++pi){
            int fi = (d0w + 2 * pi - 128) >> 1;
            float invf = __expf(-(float)fi * 0.5756462732485114f); // ln(10000)/16
            float sn, cs;
            sincosf((float)s * invf, &sn, &cs);
            float e = v[2 * pi], o = v[2 * pi + 1];
            v[2 * pi]     = e * cs - o * sn;
            v[2 * pi + 1] = o * cs + e * sn;
          }
        }
        uint4 pk;
        pk.x = pack2(v[0], v[1]); pk.y = pack2(v[2], v[3]);
        pk.z = pack2(v[4], v[5]); pk.w = pack2(v[6], v[7]);
        rp4[ml * 129 + t * 4 + (wave ^ (t & 3))] = pk;
      }
  } else {
#pragma unroll
    for(int nt = 0; nt < 8; ++nt){
      int dl = wave * 8 + nt;
#pragma unroll
      for(int mt = 0; mt < 2; ++mt){
        int jc = mt * 2 + (qd >> 1);
        int slot = ml * 129 + dl * 4 + (jc ^ (dl & 3));
        uint2 pk;
        pk.x = pack2(acc[nt][mt][0], acc[nt][mt][1]);
        pk.y = pack2(acc[nt][mt][2], acc[nt][mt][3]);
        *(reinterpret_cast<uint2*>(rp + slot * 8) + (qd & 1)) = pk;
      }
    }
  }
  __syncthreads();

  if(which < 2){
    uint16_t* dst = which ? k_t : q_t;
    const int cb = d0b >> 3;
#pragma unroll
    for(int it = 0; it < 8; ++it){
      int h = wave * 4 + (it & 3), rhalf = it >> 2;
      int tloc = rhalf * 16 + (lane >> 2), p = lane & 3;
      int row = row0 + tloc;
      uint4 val = rp4[h * 129 + tloc * 4 + p];
      size_t off = ((size_t)(b * 16 + h) * 32 + kt2) * 12288
                 + (size_t)row * 192 + ((cb ^ (tloc & 4)) + p) * 8;
      *reinterpret_cast<uint4*>(dst + off) = val;
    }
  } else {
    const int cs0 = row0 >> 3;
#pragma unroll
    for(int it = 0; it < 8; ++it){
      int h = wave * 4 + (it & 3), dhalf = it >> 2;
      int dl = dhalf * 16 + (lane >> 2), p = lane & 3;
      uint4 val = rp4[h * 129 + dl * 4 + p];
      size_t off = ((size_t)(b * 16 + h) * 32 + kt2) * 12288
                 + (size_t)(d0b + dl) * 64 + ((cs0 ^ (dl & 4)) + p) * 8;
      *reinterpret_cast<uint4*>(v_t + off) = val;
    }
  }
}

// ---------------- 4) causal flash attention v9 ----------------
// R0's proven shell (512 thr / 8 waves / 1 block-CU / double-buffered counted
// vmcnt(6)) + 2-q-tile register reuse + in-block KV-half split.
// 512 blocks: s = 15-(bx>>5) (128-row q-super, long-first), bh = bx&31.
// 8 waves = 4 row-groups (hw=wave&3, 32 rows each, 2 adjacent 16-row q-tiles)
// x 2 KV-halves (half=wave>>2): half0 does tiles [0,L/2), half1 [L/2,L) of the
// causal range L=4s+4 (KVBLK=32) CONCURRENTLY. Softmax has no max-subtraction
// -> per-half partial o (incl ones-denominator) is additive; combined by an
// in-LDS f32 reduction at the epilogue (R2-proven pattern).
// Every K/V ds_read_b128 feeds 2 MFMAs (27 reads/50 MFMA vs R0's 52/50).
// Balance: wall-iters = 2s+2; long-first dispatch backfills short blocks into
// early-freed CUs -> every CU totals exactly 34 iters.
// LDS 122,880 B (2x2 K bufs + 2x2 V bufs + 8 psw). K/V/psw/V-gather formulas
// carried verbatim from the R4/R5-verified kernel.
__global__ __launch_bounds__(512, 2) void k_attn(const uint16_t* __restrict__ q_t,
                                                 const uint16_t* __restrict__ k_t,
                                                 const uint16_t* __restrict__ v_t,
                                                 uint16_t* __restrict__ attn_out){
  // elems: K 4x6144=24576 | V 4x6656=26624 (@24576) | psw 8x1280 (@51200)
  __shared__ __align__(16) uint16_t smem[61440];
  const int tid  = threadIdx.x;
  const int wave = tid >> 6;
  const int lane = tid & 63;
  const int ml   = lane & 15;
  const int qd   = lane >> 4;
  const int hw   = wave & 3;           // row-group within the 128-row super
  const int half = wave >> 2;          // KV half
  const int bx   = blockIdx.x;
  const int bh   = bx & 31;
  const int s    = 15 - (bx >> 5);     // q-super index, long blocks first
  const int Lh   = 2 * s + 2;          // tiles per half

  uint16_t* const psw = smem + 51200 + wave * 1280;   // [32][40] per wave

  const uint16_t* kbase = k_t + (size_t)bh * 393216;
  const uint16_t* vbase = v_t + (size_t)bh * 393216;
  const int hh = bh & 15, bb = bh >> 4;

  // V gather constants (R3/R4/R5-verified)
  const int c_  = (lane & 3) ^ ((lane >> 3) & 3);
  const int s7_ = (lane >> 2) & 7;
  const int vg_ = (lane >> 2) * 64;
  const int voff0 = vg_ + ((c_ ^ s7_) * 8);
  const int voff1 = vg_ + (((4 + c_) ^ s7_) * 8);
  // PV read base: addr = vc + dt*512 + vpo (verified)
  const int vpo = ml * 32 + ((qd ^ ((ml >> 1) & 3)) * 8);

  // ---- Q fragments: 2 adjacent q-tiles, direct global->regs ----
  bf16x8 qf[2][6];
  {
    const uint16_t* qtb = q_t + ((size_t)bh * 32 + 2 * s + (hw >> 1)) * 12288;
#pragma unroll
    for(int t = 0; t < 2; ++t){
      int row = (hw & 1) * 32 + t * 16 + ml;
      const uint16_t* qr = qtb + (size_t)row * 192;
      int sw = row & 7;
#pragma unroll
      for(int kk = 0; kk < 6; ++kk)
        qf[t][kk] = load_frag(qr + (((kk * 4 + qd) ^ sw) * 8));
    }
  }

  // ones rows of all 4 V buffers (denominator source); each thread writes 2
  {
    uint32_t* o01 = (uint32_t*)(smem + 24576 + (tid >> 8) * 6656 + 6144);
    uint32_t* o23 = (uint32_t*)(smem + 24576 + (2 + (tid >> 8)) * 6656 + 6144);
    o01[tid & 255] = 0x3F803F80u;
    o23[tid & 255] = 0x3F803F80u;
  }
  asm volatile("s_waitcnt lgkmcnt(0)" ::: "memory");

  // stage KV tile kt (32 keys) of this wave's half into buffer sel:
  // 3 K-DMAs + 3 V-DMAs per wave (4 waves/half cover 12 segs each)
  auto stageKV = [&](int kt, int sel){
    const int b4 = half * 2 + sel;
#pragma unroll
    for(int it = 0; it < 3; ++it){
      int seg = hw * 3 + it;
      const uint16_t* ksrc = kbase + (size_t)(kt >> 1) * 12288 + (kt & 1) * 6144
                           + seg * 512 + lane * 8;
      gl2lds16(ksrc, smem + b4 * 6144 + seg * 512);
    }
    const int vo = (kt & 1) ? voff1 : voff0;
#pragma unroll
    for(int it = 0; it < 3; ++it){
      int seg = hw * 3 + it;
      const uint16_t* vsrc = vbase + (size_t)(kt >> 1) * 12288 + (size_t)seg * 1024 + vo;
      gl2lds16(vsrc, smem + 24576 + b4 * 6656 + seg * 512);
    }
  };

  const int kt0 = half * Lh;
  stageKV(kt0, 0);

  f32x4 o[2][13];
#pragma unroll
  for(int t = 0; t < 2; ++t)
#pragma unroll
    for(int i = 0; i < 13; ++i) o[t][i] = fzero();

  const int r0 = s * 128 + hw * 32;    // tile-0 first q-row
  const int r1 = r0 + 16;              // tile-1 first q-row
  int cur = 0;
  for(int i = 0; i < Lh; ++i){
    if(i + 1 < Lh){
      stageKV(kt0 + i + 1, cur ^ 1);
      __builtin_amdgcn_sched_barrier(0);
      asm volatile("s_waitcnt vmcnt(6)" ::: "memory");   // tile kt0+i landed
      __builtin_amdgcn_sched_barrier(0);
    } else {
      asm volatile("s_waitcnt vmcnt(0)" ::: "memory");
      __builtin_amdgcn_sched_barrier(0);
    }
    __builtin_amdgcn_s_barrier();            // [A] tile staged everywhere

    const int kl = (kt0 + i) * 32;
    if(kl <= r1 + 15){                       // wave has work this tile
      const uint16_t* kc = smem + (half * 2 + cur) * 6144;
      const uint16_t* vc = smem + 24576 + (half * 2 + cur) * 6656;
      const bool a0 = (kl <= r0 + 15);       // tile-0 active (uniform)

      f32x4 sv[2][2];
      sv[0][0] = fzero(); sv[0][1] = fzero(); sv[1][0] = fzero(); sv[1][1] = fzero();
      __builtin_amdgcn_s_setprio(1);
#pragma unroll
      for(int nt = 0; nt < 2; ++nt){
        int row = nt * 16 + ml;
#pragma unroll
        for(int kk = 0; kk < 6; ++kk){
          bf16x8 bfr = load_frag(kc + row * 192 + (((kk * 4 + qd) ^ (row & 7)) * 8));
          if(a0) sv[0][nt] = MFMA16x16(qf[0][kk], bfr, sv[0][nt]);
          sv[1][nt] = MFMA16x16(qf[1][kk], bfr, sv[1][nt]);
        }
      }
      __builtin_amdgcn_s_setprio(0);

#pragma unroll
      for(int t = 0; t < 2; ++t){
        if(t == 0 && !a0) continue;
        const int rq = r0 + t * 16;
        const bool diag = (kl + 31 > rq);
#pragma unroll
        for(int nt = 0; nt < 2; ++nt)
#pragma unroll
          for(int r = 0; r < 4; ++r){
            float v = sv[t][nt][r];
            if(diag){
              int i2 = rq + qd * 4 + r;
              int j = kl + nt * 16 + ml;
              if(j > i2) v = -1e9f;
            }
            psw[(t * 16 + qd * 4 + r) * 40 + nt * 16 + ml] = f2bf(__expf(v));
          }
      }
      bf16x8 pa0 = load_frag(psw + ml * 40 + qd * 8);
      bf16x8 pa1 = load_frag(psw + (16 + ml) * 40 + qd * 8);
      __builtin_amdgcn_s_setprio(1);
#pragma unroll
      for(int dt = 0; dt < 13; ++dt){
        bf16x8 vbf = load_frag(vc + dt * 512 + vpo);
        if(a0) o[0][dt] = MFMA16x16(pa0, vbf, o[0][dt]);
        o[1][dt] = MFMA16x16(pa1, vbf, o[1][dt]);
      }
      __builtin_amdgcn_s_setprio(0);
    }
    __builtin_amdgcn_s_barrier();            // [B] all reads of tile done
    cur ^= 1;
  }

  // ---- epilogue: cross-half reduction via LDS (all KV reads done) ----
  f32x4* red = (f32x4*)smem;                 // 8 x 832 x 16B = 106,496 B
  if(half == 1){
#pragma unroll
    for(int t = 0; t < 2; ++t)
#pragma unroll
      for(int dt = 0; dt < 13; ++dt)
        red[(hw * 2 + t) * 832 + lane * 13 + dt] = o[t][dt];
  }
  __syncthreads();
  if(half == 0){
#pragma unroll
    for(int t = 0; t < 2; ++t){
#pragma unroll
      for(int dt = 0; dt < 13; ++dt)
        o[t][dt] += red[(hw * 2 + t) * 832 + lane * 13 + dt];
      const int rq = r0 + t * 16;
#pragma unroll
      for(int r = 0; r < 4; ++r){
        int i2 = rq + qd * 4 + r;
        float inv = 1.0f / o[t][12][r];
        size_t obase = ((size_t)bb * 2048 + i2) * 3072 + hh * 192;
#pragma unroll
        for(int dt = 0; dt < 12; ++dt)
          attn_out[obase + dt * 16 + ml] = f2bf(o[t][dt][r] * inv);
      }
    }
  }
}

// ---------------- 5) out-proj GEMM: m97-style LDS-tiled, split-K=2 ----------
__global__ __launch_bounds__(256) void k_gemm_o_tile(const uint16_t* __restrict__ a,
                                                     const uint16_t* __restrict__ wt,
                                                     float* __restrict__ part){
  __shared__ __align__(16) uint16_t as[128 * 64];
  __shared__ __align__(16) uint16_t bs[128 * 64];
  const int wave = threadIdx.x >> 6, lane = threadIdx.x & 63;
  const int ml = lane & 15, qd = lane >> 4;
  const int m0 = blockIdx.y * 128, n0 = blockIdx.x * 128;
  const int kz = blockIdx.z;
  const int mo = (wave >> 1) * 64, no = (wave & 1) * 64;

  const int lrow = lane >> 3;
  const int gch  = (lane & 7) ^ (lrow & 7);
  const uint16_t* abase = a  + (size_t)(m0 + lrow) * 3072 + kz * 1536 + gch * 8;
  const uint16_t* bbase = wt + (size_t)(n0 + lrow) * 3072 + kz * 1536 + gch * 8;

  f32x4 acc[4][4];
#pragma unroll
  for(int mt = 0; mt < 4; ++mt)
#pragma unroll
    for(int nt = 0; nt < 4; ++nt) acc[mt][nt] = fzero();

  for(int kt = 0; kt < 24; ++kt){
    __syncthreads();
#pragma unroll
    for(int it = 0; it < 4; ++it){
      int seg = it * 4 + wave;
      gl2lds16(abase + (size_t)seg * 24576 + kt * 64, as + seg * 512);
      gl2lds16(bbase + (size_t)seg * 24576 + kt * 64, bs + seg * 512);
    }
    __syncthreads();
#pragma unroll
    for(int ks2 = 0; ks2 < 2; ++ks2){
      bf16x8 af[4], bfr[4];
#pragma unroll
      for(int mt = 0; mt < 4; ++mt){
        int row = mo + mt * 16 + ml;
        af[mt] = load_frag(as + row * 64 + (((ks2 * 4 + qd) ^ (row & 7)) * 8));
      }
#pragma unroll
      for(int nt = 0; nt < 4; ++nt){
        int row = no + nt * 16 + ml;
        bfr[nt] = load_frag(bs + row * 64 + (((ks2 * 4 + qd) ^ (row & 7)) * 8));
      }
#pragma unroll
      for(int mt = 0; mt < 4; ++mt)
#pragma unroll
        for(int nt = 0; nt < 4; ++nt)
          acc[mt][nt] = MFMA16x16(af[mt], bfr[nt], acc[mt][nt]);
    }
  }

  float* dst = part + (size_t)kz * 4096 * 1024;
#pragma unroll
  for(int mt = 0; mt < 4; ++mt)
#pragma unroll
    for(int nt = 0; nt < 4; ++nt)
#pragma unroll
      for(int r = 0; r < 4; ++r){
        int row = m0 + mo + mt * 16 + qd * 4 + r;
        int col = n0 + no + nt * 16 + ml;
        dst[(size_t)row * 1024 + col] = acc[mt][nt][r];
      }
}

// out = part0 + part1 (float4)
__global__ __launch_bounds__(256) void k_addout(const float* __restrict__ part,
                                                float* __restrict__ out){
  int i = blockIdx.x * 256 + threadIdx.x;
  const float4* p0 = (const float4*)part;
  const float4* p1 = p0 + (size_t)1048576;
  float4 a = p0[i], b = p1[i];
  float4 c; c.x = a.x + b.x; c.y = a.y + b.y; c.z = a.z + b.z; c.w = a.w + b.w;
  ((float4*)out)[i] = c;
}

// ---------------- launch ----------------

extern "C" void kernel_launch(void* const* d_in, const int* in_sizes, int n_in,
                              void* d_out, int out_size, void* d_ws, size_t ws_size,
                              hipStream_t stream) {
  (void)in_sizes; (void)n_in; (void)out_size; (void)ws_size;
  const float* x      = (const float*)d_in[0];
  const float* w_down = (const float*)d_in[2];
  const float* rms_w  = (const float*)d_in[3];
  const float* w_up   = (const float*)d_in[4];
  const float* w_o    = (const float*)d_in[5];
  float* out = (float*)d_out;

  char* ws = (char*)d_ws;
  uint16_t* h_bf   = (uint16_t*)(ws);                     // 1,572,864 B
  uint16_t* w_up_t = (uint16_t*)(ws + 1572864);           // 3,538,944 B
  uint16_t* w_o_t  = (uint16_t*)(ws + 5111808);           // 6,291,456 B
  uint16_t* w_dn_t = (uint16_t*)(ws + 11403264);          //   393,216 B
  uint16_t* q_tb   = (uint16_t*)(ws + 11796480);          // 25,165,824 B
  uint16_t* k_tb   = (uint16_t*)(ws + 36962304);          // 25,165,824 B
  uint16_t* v_tb   = (uint16_t*)(ws + 62128128);          // 25,165,824 B
  uint16_t* attnO  = (uint16_t*)(ws + 87293952);          // 25,165,824 B
  float*    part   = (float*)(ws + 11796480);             // alias q_tb/k_tb (dead after attn)

  k_transpose_cvt<<<dim3(288, 6), 256, 0, stream>>>(w_up, w_up_t, 192, 9216);
  k_transpose_cvt<<<dim3(32, 96), 256, 0, stream>>>(w_o,  w_o_t,  3072, 1024);
  k_transpose_cvt<<<dim3(6, 32),  256, 0, stream>>>(w_down, w_dn_t, 1024, 192);
  k_down_mfma<<<128, 256, 0, stream>>>(x, w_dn_t, rms_w, h_bf);
  k_gemm_up<<<dim3(18, 128), 256, 0, stream>>>(h_bf, w_up_t, q_tb, k_tb, v_tb);
  k_attn<<<512, 512, 0, stream>>>(q_tb, k_tb, v_tb, attnO);
  k_gemm_o_tile<<<dim3(8, 32, 2), 256, 0, stream>>>(attnO, w_o_t, part);
  k_addout<<<4096, 256, 0, stream>>>(part, out);
}

// Round 8
// 336.312 us; speedup vs baseline: 1.1153x; 1.0196x over previous
//
#include <hip/hip_runtime.h>
#include <stdint.h>
#include <stddef.h>

// ---------------- common helpers ----------------

typedef __bf16 bf16x8 __attribute__((ext_vector_type(8)));
typedef float  f32x4  __attribute__((ext_vector_type(4)));

#define MFMA16x16(a,b,c) __builtin_amdgcn_mfma_f32_16x16x32_bf16((a),(b),(c),0,0,0)

__device__ __forceinline__ uint16_t f2bf(float f){
  union { float f; uint32_t u; } v; v.f = f;
  uint32_t u = v.u + 0x7fffu + ((v.u >> 16) & 1u);
  return (uint16_t)(u >> 16);
}
__device__ __forceinline__ bf16x8 load_frag(const uint16_t* p){
  uint4 u = *reinterpret_cast<const uint4*>(p);
  return __builtin_bit_cast(bf16x8, u);
}
__device__ __forceinline__ f32x4 fzero(){
  f32x4 z = {0.f, 0.f, 0.f, 0.f};
  return z;
}
__device__ __forceinline__ uint32_t pack2(float a, float b){
  return (uint32_t)f2bf(a) | ((uint32_t)f2bf(b) << 16);
}
// async global->LDS DMA, 16B per lane, LDS dst = wave-uniform base + lane*16
__device__ __forceinline__ void gl2lds16(const uint16_t* g, uint16_t* l){
  __builtin_amdgcn_global_load_lds(
      (const __attribute__((address_space(1))) uint32_t*)g,
      (__attribute__((address_space(3))) uint32_t*)l,
      16, 0, 0);
}

// ---------------- 1) transpose + f32->bf16 convert ----------------
__global__ __launch_bounds__(256) void k_transpose_cvt(const float* __restrict__ in,
                                                       uint16_t* __restrict__ out,
                                                       int R, int C){
  __shared__ float t[32][33];
  const int tc = blockIdx.x * 32;
  const int tr = blockIdx.y * 32;
  const int j = threadIdx.x & 31, i0 = threadIdx.x >> 5;
  for(int ii = 0; ii < 4; ++ii){
    int r = i0 + ii * 8;
    t[r][j] = in[(size_t)(tr + r) * C + tc + j];
  }
  __syncthreads();
  for(int ii = 0; ii < 4; ++ii){
    int c = i0 + ii * 8;
    out[(size_t)(tc + c) * R + tr + j] = f2bf(t[j][c]);
  }
}

// ---------------- 2) down-proj + RMSNorm via MFMA ----------------
__global__ __launch_bounds__(256) void k_down_mfma(const float* __restrict__ x,
                                                   const uint16_t* __restrict__ wdt,
                                                   const float* __restrict__ rms_w,
                                                   uint16_t* __restrict__ h_out){
  __shared__ __align__(16) uint16_t as[32 * 64];
  __shared__ float hsq[32];
  const int tid  = threadIdx.x;
  const int wave = tid >> 6, lane = tid & 63;
  const int ml = lane & 15, qd = lane >> 4;
  const int m0 = blockIdx.x * 32;
  const int n0w = wave * 48;
  if(tid < 32) hsq[tid] = 0.f;

  f32x4 acc[2][3];
#pragma unroll
  for(int mt = 0; mt < 2; ++mt)
#pragma unroll
    for(int nt = 0; nt < 3; ++nt) acc[mt][nt] = fzero();

  const int srow = tid >> 3, sc = tid & 7;
  for(int kt = 0; kt < 16; ++kt){
    const float* src = x + (size_t)(m0 + srow) * 1024 + kt * 64 + sc * 8;
    float4 a = *reinterpret_cast<const float4*>(src);
    float4 b = *reinterpret_cast<const float4*>(src + 4);
    uint4 pk;
    pk.x = pack2(a.x, a.y); pk.y = pack2(a.z, a.w);
    pk.z = pack2(b.x, b.y); pk.w = pack2(b.z, b.w);
    __syncthreads();
    *reinterpret_cast<uint4*>(as + srow * 64 + ((sc ^ (srow & 7)) * 8)) = pk;
    __syncthreads();
#pragma unroll
    for(int kk = 0; kk < 2; ++kk){
      bf16x8 af[2];
#pragma unroll
      for(int mt = 0; mt < 2; ++mt){
        int row = mt * 16 + ml;
        af[mt] = load_frag(as + row * 64 + (((kk * 4 + qd) ^ (row & 7)) * 8));
      }
#pragma unroll
      for(int nt = 0; nt < 3; ++nt){
        bf16x8 bfr = load_frag(wdt + (size_t)(n0w + nt * 16 + ml) * 1024 + kt * 64 + kk * 32 + qd * 8);
#pragma unroll
        for(int mt = 0; mt < 2; ++mt)
          acc[mt][nt] = MFMA16x16(af[mt], bfr, acc[mt][nt]);
      }
    }
  }
  __syncthreads();
#pragma unroll
  for(int mt = 0; mt < 2; ++mt)
#pragma unroll
    for(int r = 0; r < 4; ++r){
      float s = acc[mt][0][r]*acc[mt][0][r] + acc[mt][1][r]*acc[mt][1][r] + acc[mt][2][r]*acc[mt][2][r];
#pragma unroll
      for(int off = 1; off < 16; off <<= 1) s += __shfl_xor(s, off);
      if(ml == 0) atomicAdd(&hsq[mt * 16 + qd * 4 + r], s);
    }
  __syncthreads();
  float rw[3];
#pragma unroll
  for(int nt = 0; nt < 3; ++nt) rw[nt] = rms_w[n0w + nt * 16 + ml];
#pragma unroll
  for(int mt = 0; mt < 2; ++mt)
#pragma unroll
    for(int r = 0; r < 4; ++r){
      int row = mt * 16 + qd * 4 + r;
      float scl = rsqrtf(hsq[row] * (1.0f / 192.0f) + 1e-6f);
#pragma unroll
      for(int nt = 0; nt < 3; ++nt)
        h_out[(size_t)(m0 + row) * 192 + n0w + nt * 16 + ml] = f2bf(acc[mt][nt][r] * scl * rw[nt]);
    }
}

// ---------------- 3) up-proj GEMM v2: LDS repack -> full-line stores --------
__global__ __launch_bounds__(256) void k_gemm_up(const uint16_t* __restrict__ hmat,
                                                 const uint16_t* __restrict__ wt,
                                                 uint16_t* __restrict__ q_t,
                                                 uint16_t* __restrict__ k_t,
                                                 uint16_t* __restrict__ v_t){
  __shared__ __align__(16) uint16_t rp[16 * 129 * 8];   // 33,024 B
  const int wave = threadIdx.x >> 6, lane = threadIdx.x & 63;
  const int ml = lane & 15, qd = lane >> 4;
  const int m0 = blockIdx.y * 32;
  const int bx = blockIdx.x;
  const int which = bx / 6;                // 0=q 1=k 2=v
  const int d0b = (bx % 6) * 32;
  const int n0w = bx * 512 + wave * 128;
  const int d0w = d0b + wave * 8;

  bf16x8 af[2][6];
#pragma unroll
  for(int mt = 0; mt < 2; ++mt)
#pragma unroll
    for(int kk = 0; kk < 6; ++kk)
      af[mt][kk] = load_frag(hmat + (size_t)(m0 + mt * 16 + ml) * 192 + kk * 32 + qd * 8);

  f32x4 acc[8][2];
#pragma unroll
  for(int nt = 0; nt < 8; ++nt){ acc[nt][0] = fzero(); acc[nt][1] = fzero(); }
#pragma unroll
  for(int nt = 0; nt < 8; ++nt){
#pragma unroll
    for(int kk = 0; kk < 6; ++kk){
      bf16x8 b = load_frag(wt + (size_t)(n0w + nt * 16 + ml) * 192 + kk * 32 + qd * 8);
      acc[nt][0] = MFMA16x16(af[0][kk], b, acc[nt][0]);
      acc[nt][1] = MFMA16x16(af[1][kk], b, acc[nt][1]);
    }
  }

  const int b   = m0 >> 11;
  const int s0  = m0 & 2047;
  const int kt2 = s0 >> 6;
  const int row0 = s0 & 63;                // 32-aligned: rs bits come from t
  uint4* rp4 = (uint4*)rp;

  if(which < 2){
    const float qs = which ? 1.0f : 0.07216878364870322f;   // fold 1/sqrt(192) into Q
    const bool rope = (d0w >= 128) && (d0w < 160);
#pragma unroll
    for(int mt = 0; mt < 2; ++mt)
#pragma unroll
      for(int r = 0; r < 4; ++r){
        int t = mt * 16 + qd * 4 + r;
        int s = s0 + t;
        float v[8];
#pragma unroll
        for(int nt = 0; nt < 8; ++nt) v[nt] = acc[nt][mt][r] * qs;
        if(rope){
#pragma unroll
          for(int pi = 0; pi < 4; ++pi){
            int fi = (d0w + 2 * pi - 128) >> 1;
            float invf = __expf(-(float)fi * 0.5756462732485114f); // ln(10000)/16
            float sn, cs;
            sincosf((float)s * invf, &sn, &cs);
            float e = v[2 * pi], o = v[2 * pi + 1];
            v[2 * pi]     = e * cs - o * sn;
            v[2 * pi + 1] = o * cs + e * sn;
          }
        }
        uint4 pk;
        pk.x = pack2(v[0], v[1]); pk.y = pack2(v[2], v[3]);
        pk.z = pack2(v[4], v[5]); pk.w = pack2(v[6], v[7]);
        rp4[ml * 129 + t * 4 + (wave ^ (t & 3))] = pk;
      }
  } else {
#pragma unroll
    for(int nt = 0; nt < 8; ++nt){
      int dl = wave * 8 + nt;
#pragma unroll
      for(int mt = 0; mt < 2; ++mt){
        int jc = mt * 2 + (qd >> 1);
        int slot = ml * 129 + dl * 4 + (jc ^ (dl & 3));
        uint2 pk;
        pk.x = pack2(acc[nt][mt][0], acc[nt][mt][1]);
        pk.y = pack2(acc[nt][mt][2], acc[nt][mt][3]);
        *(reinterpret_cast<uint2*>(rp + slot * 8) + (qd & 1)) = pk;
      }
    }
  }
  __syncthreads();

  if(which < 2){
    uint16_t* dst = which ? k_t : q_t;
    const int cb = d0b >> 3;
#pragma unroll
    for(int it = 0; it < 8; ++it){
      int h = wave * 4 + (it & 3), rhalf = it >> 2;
      int tloc = rhalf * 16 + (lane >> 2), p = lane & 3;
      int row = row0 + tloc;
      uint4 val = rp4[h * 129 + tloc * 4 + p];
      size_t off = ((size_t)(b * 16 + h) * 32 + kt2) * 12288
                 + (size_t)row * 192 + ((cb ^ (tloc & 4)) + p) * 8;
      *reinterpret_cast<uint4*>(dst + off) = val;
    }
  } else {
    const int cs0 = row0 >> 3;
#pragma unroll
    for(int it = 0; it < 8; ++it){
      int h = wave * 4 + (it & 3), dhalf = it >> 2;
      int dl = dhalf * 16 + (lane >> 2), p = lane & 3;
      uint4 val = rp4[h * 129 + dl * 4 + p];
      size_t off = ((size_t)(b * 16 + h) * 32 + kt2) * 12288
                 + (size_t)(d0b + dl) * 64 + ((cs0 ^ (dl & 4)) + p) * 8;
      *reinterpret_cast<uint4*>(v_t + off) = val;
    }
  }
}

// ---------------- 4) causal flash attention v10 ----------------
// 512 blocks x 1024 threads (16 waves = 4 waves/SIMD, single block/CU).
// Rationale: R0/R3/R6 all plateaued at MfmaUtil 21-25% with 2 waves/SIMD --
// phase-locked QK^T->exp->PV alternates matrix/vector pipes idle. Multi-block
// co-residency never materialized (R1-R5); a 1024-thr block guarantees 16
// waves on one CU. Per-wave state = R0's proven 16-row shape (~116 VGPR,
// fits the 128-cap that 4 waves/SIMD requires; launch_bounds(1024,1)).
// 16 waves = 8 row-groups (hw, 16 rows of the 128-row q-super) x 2 KV-halves
// (half0 tiles [0,Lh), half1 [Lh,2Lh), Lh=2s+2, KVBLK=32, concurrent; o is
// additive -- no max-subtraction -- combined by in-LDS f32 reduction, R2/R6-
// proven). K/V double-buffered per half, 3 DMAs/wave/iter, counted vmcnt(3).
// s = 15-(bx>>5) long-first => CU pairs (s,15-s), 34 wall-iters each; both
// blocks of a CU share bh (256%32==0) => same-XCD KV L2 reuse.
// All K/V/psw/V-gather/diag formulas verbatim from the R6-verified kernel.
__global__ __launch_bounds__(1024, 1) void k_attn(const uint16_t* __restrict__ q_t,
                                                  const uint16_t* __restrict__ k_t,
                                                  const uint16_t* __restrict__ v_t,
                                                  uint16_t* __restrict__ attn_out){
  // elems: K 4x6144=24576 | V 4x6656=26624 (@24576) | psw 16x640 (@51200)
  __shared__ __align__(16) uint16_t smem[61440];
  const int tid  = threadIdx.x;
  const int wave = tid >> 6;
  const int lane = tid & 63;
  const int ml   = lane & 15;
  const int qd   = lane >> 4;
  const int hw   = wave & 7;           // row-group (16 rows) in the q-super
  const int half = wave >> 3;          // KV half
  const int bx   = blockIdx.x;
  const int bh   = bx & 31;
  const int s    = 15 - (bx >> 5);     // q-super index, long blocks first
  const int Lh   = 2 * s + 2;          // 32-key tiles per half

  uint16_t* const psw = smem + 51200 + wave * 640;   // [16][40] per wave

  const uint16_t* kbase = k_t + (size_t)bh * 393216;
  const uint16_t* vbase = v_t + (size_t)bh * 393216;
  const int hh = bh & 15, bb = bh >> 4;

  // V gather constants (R3-R6-verified)
  const int c_  = (lane & 3) ^ ((lane >> 3) & 3);
  const int s7_ = (lane >> 2) & 7;
  const int vg_ = (lane >> 2) * 64;
  const int voff0 = vg_ + ((c_ ^ s7_) * 8);
  const int voff1 = vg_ + (((4 + c_) ^ s7_) * 8);
  // PV read base: addr = vc + dt*512 + vpo (verified)
  const int vpo = ml * 32 + ((qd ^ ((ml >> 1) & 3)) * 8);

  // ---- Q fragments: wave's 16 rows, direct global->regs ----
  bf16x8 qf[6];
  {
    const uint16_t* qtb = q_t + ((size_t)bh * 32 + 2 * s + (hw >> 2)) * 12288;
    int row = (hw & 3) * 16 + ml;
    const uint16_t* qr = qtb + (size_t)row * 192;
    int sw = row & 7;
#pragma unroll
    for(int kk = 0; kk < 6; ++kk)
      qf[kk] = load_frag(qr + (((kk * 4 + qd) ^ sw) * 8));
  }

  // ones rows of all 4 V buffers (denominator source); 1024 thr -> 1 u32 each
  ((uint32_t*)(smem + 24576 + (tid >> 8) * 6656 + 6144))[tid & 255] = 0x3F803F80u;
  asm volatile("s_waitcnt lgkmcnt(0)" ::: "memory");

  // stage KV tile kt (32 keys) of this wave's half into buffer sel:
  // 24 segs per half (12 K + 12 V), 8 waves -> 3 segs/wave
  auto stageKV = [&](int kt, int sel){
    const int b4 = half * 2 + sel;
    const int vo = (kt & 1) ? voff1 : voff0;
#pragma unroll
    for(int it = 0; it < 3; ++it){
      int seg = hw * 3 + it;
      if(seg < 12){
        const uint16_t* ksrc = kbase + (size_t)(kt >> 1) * 12288 + (kt & 1) * 6144
                             + seg * 512 + lane * 8;
        gl2lds16(ksrc, smem + b4 * 6144 + seg * 512);
      } else {
        int vs = seg - 12;
        const uint16_t* vsrc = vbase + (size_t)(kt >> 1) * 12288 + (size_t)vs * 1024 + vo;
        gl2lds16(vsrc, smem + 24576 + b4 * 6656 + vs * 512);
      }
    }
  };

  const int kt0 = half * Lh;
  stageKV(kt0, 0);

  f32x4 o[13];
#pragma unroll
  for(int i = 0; i < 13; ++i) o[i] = fzero();

  const int r0 = s * 128 + hw * 16;    // wave's first global q-row
  int cur = 0;
  for(int i = 0; i < Lh; ++i){
    if(i + 1 < Lh){
      stageKV(kt0 + i + 1, cur ^ 1);
      __builtin_amdgcn_sched_barrier(0);
      asm volatile("s_waitcnt vmcnt(3)" ::: "memory");   // tile kt0+i landed
      __builtin_amdgcn_sched_barrier(0);
    } else {
      asm volatile("s_waitcnt vmcnt(0)" ::: "memory");
      __builtin_amdgcn_sched_barrier(0);
    }
    __builtin_amdgcn_s_barrier();            // [A] tile staged everywhere

    const int kl = (kt0 + i) * 32;
    if(kl <= r0 + 15){                       // wave has work this tile
      const uint16_t* kc = smem + (half * 2 + cur) * 6144;
      const uint16_t* vc = smem + 24576 + (half * 2 + cur) * 6656;

      float pp[2][4];
      __builtin_amdgcn_s_setprio(1);
#pragma unroll
      for(int nt = 0; nt < 2; ++nt){
        f32x4 a = fzero();
        int row = nt * 16 + ml;
#pragma unroll
        for(int kk = 0; kk < 6; ++kk){
          bf16x8 bfr = load_frag(kc + row * 192 + (((kk * 4 + qd) ^ (row & 7)) * 8));
          a = MFMA16x16(qf[kk], bfr, a);
        }
#pragma unroll
        for(int r = 0; r < 4; ++r) pp[nt][r] = a[r];
      }
      __builtin_amdgcn_s_setprio(0);

      const bool diag = (kl + 31 > r0);
#pragma unroll
      for(int nt = 0; nt < 2; ++nt)
#pragma unroll
        for(int r = 0; r < 4; ++r){
          float v = pp[nt][r];
          if(diag){
            int i2 = r0 + qd * 4 + r;
            int j = kl + nt * 16 + ml;
            if(j > i2) v = -1e9f;
          }
          psw[(qd * 4 + r) * 40 + nt * 16 + ml] = f2bf(__expf(v));
        }
      bf16x8 pa = load_frag(psw + ml * 40 + qd * 8);
      __builtin_amdgcn_s_setprio(1);
#pragma unroll
      for(int dt = 0; dt < 13; ++dt){
        bf16x8 vbf = load_frag(vc + dt * 512 + vpo);
        o[dt] = MFMA16x16(pa, vbf, o[dt]);
      }
      __builtin_amdgcn_s_setprio(0);
    }
    __builtin_amdgcn_s_barrier();            // [B] all reads of tile done
    cur ^= 1;
  }

  // ---- epilogue: cross-half reduction via LDS (all KV/psw reads done) ----
  f32x4* red = (f32x4*)smem;                 // 8 x 64 x 13 x 16B = 106,496 B
  if(half == 1){
#pragma unroll
    for(int dt = 0; dt < 13; ++dt)
      red[(hw * 64 + lane) * 13 + dt] = o[dt];
  }
  __syncthreads();
  if(half == 0){
#pragma unroll
    for(int dt = 0; dt < 13; ++dt)
      o[dt] += red[(hw * 64 + lane) * 13 + dt];
#pragma unroll
    for(int r = 0; r < 4; ++r){
      int i2 = r0 + qd * 4 + r;
      float inv = 1.0f / o[12][r];
      size_t obase = ((size_t)bb * 2048 + i2) * 3072 + hh * 192;
#pragma unroll
      for(int dt = 0; dt < 12; ++dt)
        attn_out[obase + dt * 16 + ml] = f2bf(o[dt][r] * inv);
    }
  }
}

// ---------------- 5) out-proj GEMM: m97-style LDS-tiled, split-K=2 ----------
__global__ __launch_bounds__(256) void k_gemm_o_tile(const uint16_t* __restrict__ a,
                                                     const uint16_t* __restrict__ wt,
                                                     float* __restrict__ part){
  __shared__ __align__(16) uint16_t as[128 * 64];
  __shared__ __align__(16) uint16_t bs[128 * 64];
  const int wave = threadIdx.x >> 6, lane = threadIdx.x & 63;
  const int ml = lane & 15, qd = lane >> 4;
  const int m0 = blockIdx.y * 128, n0 = blockIdx.x * 128;
  const int kz = blockIdx.z;
  const int mo = (wave >> 1) * 64, no = (wave & 1) * 64;

  const int lrow = lane >> 3;
  const int gch  = (lane & 7) ^ (lrow & 7);
  const uint16_t* abase = a  + (size_t)(m0 + lrow) * 3072 + kz * 1536 + gch * 8;
  const uint16_t* bbase = wt + (size_t)(n0 + lrow) * 3072 + kz * 1536 + gch * 8;

  f32x4 acc[4][4];
#pragma unroll
  for(int mt = 0; mt < 4; ++mt)
#pragma unroll
    for(int nt = 0; nt < 4; ++nt) acc[mt][nt] = fzero();

  for(int kt = 0; kt < 24; ++kt){
    __syncthreads();
#pragma unroll
    for(int it = 0; it < 4; ++it){
      int seg = it * 4 + wave;
      gl2lds16(abase + (size_t)seg * 24576 + kt * 64, as + seg * 512);
      gl2lds16(bbase + (size_t)seg * 24576 + kt * 64, bs + seg * 512);
    }
    __syncthreads();
#pragma unroll
    for(int ks2 = 0; ks2 < 2; ++ks2){
      bf16x8 af[4], bfr[4];
#pragma unroll
      for(int mt = 0; mt < 4; ++mt){
        int row = mo + mt * 16 + ml;
        af[mt] = load_frag(as + row * 64 + (((ks2 * 4 + qd) ^ (row & 7)) * 8));
      }
#pragma unroll
      for(int nt = 0; nt < 4; ++nt){
        int row = no + nt * 16 + ml;
        bfr[nt] = load_frag(bs + row * 64 + (((ks2 * 4 + qd) ^ (row & 7)) * 8));
      }
#pragma unroll
      for(int mt = 0; mt < 4; ++mt)
#pragma unroll
        for(int nt = 0; nt < 4; ++nt)
          acc[mt][nt] = MFMA16x16(af[mt], bfr[nt], acc[mt][nt]);
    }
  }

  float* dst = part + (size_t)kz * 4096 * 1024;
#pragma unroll
  for(int mt = 0; mt < 4; ++mt)
#pragma unroll
    for(int nt = 0; nt < 4; ++nt)
#pragma unroll
      for(int r = 0; r < 4; ++r){
        int row = m0 + mo + mt * 16 + qd * 4 + r;
        int col = n0 + no + nt * 16 + ml;
        dst[(size_t)row * 1024 + col] = acc[mt][nt][r];
      }
}

// out = part0 + part1 (float4)
__global__ __launch_bounds__(256) void k_addout(const float* __restrict__ part,
                                                float* __restrict__ out){
  int i = blockIdx.x * 256 + threadIdx.x;
  const float4* p0 = (const float4*)part;
  const float4* p1 = p0 + (size_t)1048576;
  float4 a = p0[i], b = p1[i];
  float4 c; c.x = a.x + b.x; c.y = a.y + b.y; c.z = a.z + b.z; c.w = a.w + b.w;
  ((float4*)out)[i] = c;
}

// ---------------- launch ----------------

extern "C" void kernel_launch(void* const* d_in, const int* in_sizes, int n_in,
                              void* d_out, int out_size, void* d_ws, size_t ws_size,
                              hipStream_t stream) {
  (void)in_sizes; (void)n_in; (void)out_size; (void)ws_size;
  const float* x      = (const float*)d_in[0];
  const float* w_down = (const float*)d_in[2];
  const float* rms_w  = (const float*)d_in[3];
  const float* w_up   = (const float*)d_in[4];
  const float* w_o    = (const float*)d_in[5];
  float* out = (float*)d_out;

  char* ws = (char*)d_ws;
  uint16_t* h_bf   = (uint16_t*)(ws);                     // 1,572,864 B
  uint16_t* w_up_t = (uint16_t*)(ws + 1572864);           // 3,538,944 B
  uint16_t* w_o_t  = (uint16_t*)(ws + 5111808);           // 6,291,456 B
  uint16_t* w_dn_t = (uint16_t*)(ws + 11403264);          //   393,216 B
  uint16_t* q_tb   = (uint16_t*)(ws + 11796480);          // 25,165,824 B
  uint16_t* k_tb   = (uint16_t*)(ws + 36962304);          // 25,165,824 B
  uint16_t* v_tb   = (uint16_t*)(ws + 62128128);          // 25,165,824 B
  uint16_t* attnO  = (uint16_t*)(ws + 87293952);          // 25,165,824 B
  float*    part   = (float*)(ws + 11796480);             // alias q_tb/k_tb (dead after attn)

  k_transpose_cvt<<<dim3(288, 6), 256, 0, stream>>>(w_up, w_up_t, 192, 9216);
  k_transpose_cvt<<<dim3(32, 96), 256, 0, stream>>>(w_o,  w_o_t,  3072, 1024);
  k_transpose_cvt<<<dim3(6, 32),  256, 0, stream>>>(w_down, w_dn_t, 1024, 192);
  k_down_mfma<<<128, 256, 0, stream>>>(x, w_dn_t, rms_w, h_bf);
  k_gemm_up<<<dim3(18, 128), 256, 0, stream>>>(h_bf, w_up_t, q_tb, k_tb, v_tb);
  k_attn<<<512, 1024, 0, stream>>>(q_tb, k_tb, v_tb, attnO);
  k_gemm_o_tile<<<dim3(8, 32, 2), 256, 0, stream>>>(attnO, w_o_t, part);
  k_addout<<<4096, 256, 0, stream>>>(part, out);
}